// Round 3
// baseline (7755.760 us; speedup 1.0000x reference)
//
#include <hip/hip_runtime.h>
#include <math.h>

#define EPSF 1e-5f

typedef __attribute__((ext_vector_type(2))) float f2;
typedef __attribute__((ext_vector_type(4))) float f4;
typedef __attribute__((ext_vector_type(4))) unsigned int u32x4;

// packed fp32 FMA with x broadcast via op_sel (lo or hi half of the x pair)
#define PK_FMA_LO(ACC, W, X) \
    asm("v_pk_fma_f32 %0, %1, %2, %0 op_sel:[0,0,0] op_sel_hi:[1,0,1]" \
        : "+v"(ACC) : "v"(W), "v"(X))
#define PK_FMA_HI(ACC, W, X) \
    asm("v_pk_fma_f32 %0, %1, %2, %0 op_sel:[0,1,0] op_sel_hi:[1,1,1]" \
        : "+v"(ACC) : "v"(W), "v"(X))

// mixed-precision FMA: fp32 acc += fp16(half of W) * fp32 H
// op_sel_hi[0]=1 -> src0 is fp16; op_sel[0] picks lo/hi half. src1/src2 fp32.
#define FMA_MIX_LO(ACC, W, H) \
    asm("v_fma_mix_f32 %0, %1, %2, %0 op_sel:[0,0,0] op_sel_hi:[1,0,0]" \
        : "+v"(ACC) : "v"(W), "v"(H))
#define FMA_MIX_HI(ACC, W, H) \
    asm("v_fma_mix_f32 %0, %1, %2, %0 op_sel:[1,0,0] op_sel_hi:[1,0,0]" \
        : "+v"(ACC) : "v"(W), "v"(H))

// DPP helper: v += value from lane (i - N) within the 16-lane DPP row (0 if OOB)
template<int CTRL>
__device__ __forceinline__ float dpp_add(float v) {
    int s = __builtin_amdgcn_update_dpp(0, __float_as_int(v), CTRL, 0xf, 0xf, true);
    return v + __int_as_float(s);
}

// hq swizzle: +4 floats of pad per 16 (stride 20). ds_read_b128 at l*80B ->
// bank-quad (5*l)%8 balanced -> ideal throughput, no conflicts (m136).
#define HQ(d) ((d) + (((d) >> 4) << 2))

// ---------------- prep: weight transposes + bool-dtype detect ----------------
// WhhP: per-thread register layout for k_gru2 (1024 threads).
//   thread tid: group g=tid>>4 owns rows g*12..+12; lane l=tid&15 owns dims l*16..+16.
//   u32 idx = (q*1024 + tid)*4 + j, pair pp=q*4+j (0..95), r=pp>>3, p=pp&7.
//   value = pack_fp16(Whh[row][col], Whh[row][col+1]), row=g*12+r, col=l*16+2p.
__global__ __launch_bounds__(256) void k_prep(
    const float* __restrict__ Wih, const float* __restrict__ Whh,
    const float* __restrict__ W2, const float* __restrict__ W3,
    const unsigned char* __restrict__ fmask,
    unsigned int* __restrict__ WhhP, float* __restrict__ WxT,
    float* __restrict__ W2T, float* __restrict__ W3T, int* __restrict__ flag)
{
    int idx = blockIdx.x * 256 + threadIdx.x;
    if (idx < 98304) {                  // Whh -> register-resident layout (1024-thr)
        int q = idx >> 12;
        int ttid = (idx >> 2) & 1023;
        int j3 = idx & 3;
        int pp = q * 4 + j3;
        int r = pp >> 3, p = pp & 7;
        int row = (ttid >> 4) * 12 + r;
        int col = (ttid & 15) * 16 + p * 2;
        union { _Float16 h[2]; unsigned int u; } pk;
        pk.h[0] = (_Float16)Whh[row * 256 + col];
        pk.h[1] = (_Float16)Whh[row * 256 + col + 1];
        WhhP[idx] = pk.u;
    }
    if (idx < 105984) {                 // Wih[768][138] x-part -> WxT[128][768]
        int j = idx / 138, k = idx % 138;
        if (k < 128) WxT[k * 768 + j] = Wih[idx];
    }
    if (idx < 409600) {                 // W[co][ci][5][5] -> WT[tap][ci][co]
        int co = idx / 3200, r = idx % 3200;
        int ci = r / 25, tap = r % 25;
        int dst = (tap * 128 + ci) * 128 + co;
        W2T[dst] = W2[idx];
        W3T[dst] = W3[idx];
    }
    if (idx == 0) {                     // bool stored as int32? bytes 1,2,3 of each word all zero
        int nz = 0;
        for (int i = 0; i < 4096; i++) if ((i & 3) != 0) nz |= fmask[i];
        *flag = nz ? 0 : 1;
    }
}

// ---------------- conv1: [32,1,1024,40] -> X1[b][t][m1(8)][co(128)] ----------------
__global__ __launch_bounds__(256) void k_conv1(
    const float* __restrict__ X, const float* __restrict__ W1,
    const float* __restrict__ bb, const float* __restrict__ gg,
    const float* __restrict__ be, const float* __restrict__ mm_,
    const float* __restrict__ vv, float* __restrict__ X1)
{
    __shared__ __align__(16) float xs[8][44];
    __shared__ __align__(16) float ws[25][128];
    __shared__ float sc[128], sh[128];
    int bid = blockIdx.x;
    int b = bid >> 8, t0 = (bid & 255) << 2;
    int tid = threadIdx.x;
    for (int e = tid; e < 8 * 44; e += 256) {
        int tt = e / 44, mm = e % 44;
        int gt = t0 + tt - 2, gm = mm - 2;
        float val = 0.f;
        if (gt >= 0 && gt < 1024 && gm >= 0 && gm < 40)
            val = X[(b * 1024 + gt) * 40 + gm];
        xs[tt][mm] = val;
    }
    for (int e = tid; e < 3200; e += 256) {
        int tap = e >> 7, co = e & 127;
        ws[tap][co] = W1[co * 25 + tap];
    }
    if (tid < 128) {
        float s = gg[tid] / sqrtf(vv[tid] + EPSF);
        sc[tid] = s;
        sh[tid] = (bb[tid] - mm_[tid]) * s + be[tid];
    }
    __syncthreads();
    int cog = tid >> 5;          // 8 groups x 16 co
    int m1i = (tid >> 2) & 7;    // pooled mel
    int tp  = tid & 3;           // t'
    int co0 = cog * 16;
    float val[5][16];
#pragma unroll
    for (int p = 0; p < 5; p++)
#pragma unroll
        for (int i = 0; i < 16; i++) val[p][i] = 0.f;
#pragma unroll
    for (int dt = 0; dt < 5; dt++) {
#pragma unroll
        for (int dm = 0; dm < 5; dm++) {
            float w[16];
#pragma unroll
            for (int i = 0; i < 16; i += 4)
                *(float4*)&w[i] = *(const float4*)&ws[dt * 5 + dm][co0 + i];
#pragma unroll
            for (int p = 0; p < 5; p++) {
                float x = xs[tp + dt][m1i * 5 + p + dm];
#pragma unroll
                for (int i = 0; i < 16; i++) val[p][i] = fmaf(x, w[i], val[p][i]);
            }
        }
    }
    float outv[16];
#pragma unroll
    for (int i = 0; i < 16; i++) {
        float s = sc[co0 + i], h = sh[co0 + i];
        float mx = 0.f;
#pragma unroll
        for (int p = 0; p < 5; p++) {
            float y = fmaf(val[p][i], s, h);
            y = fmaxf(y, 0.f);
            mx = fmaxf(mx, y);
        }
        outv[i] = mx;
    }
    float* dst = &X1[(((long)(b * 1024 + t0 + tp)) * 8 + m1i) * 128 + co0];
#pragma unroll
    for (int i = 0; i < 16; i += 4) *(float4*)&dst[i] = *(float4*)&outv[i];
}

// -------- conv2 v4: pk_fma + 2 t-rows/thread (w-reads amortized 2x) --------
__global__ __attribute__((amdgpu_waves_per_eu(2, 2))) __launch_bounds__(256) void k_conv2(
    const float* __restrict__ X1, const float* __restrict__ W2T,
    const float* __restrict__ bb, const float* __restrict__ gg,
    const float* __restrict__ be, const float* __restrict__ mm_,
    const float* __restrict__ vv, float* __restrict__ X2)
{
    __shared__ __align__(16) float xs[36 * 196];     // [tt][ci*12 + m]
    __shared__ __align__(16) float ws[5 * 16 * 132]; // [dm][ci][co(128, pad 132)]
    __shared__ float sc[128], sh[128];
    int bid = blockIdx.x;
    int t0 = (bid & 31) << 5, b = bid >> 5;
    int tid = threadIdx.x;
    int tp = tid & 15, cog = tid >> 4;
    if (tid < 128) {
        float s = gg[tid] / sqrtf(vv[tid] + EPSF);
        sc[tid] = s;
        sh[tid] = (bb[tid] - mm_[tid]) * s + be[tid];
    }
    f2 accp[2][4][8];                    // [t-half][co pair][m]
#pragma unroll
    for (int th = 0; th < 2; th++)
#pragma unroll
        for (int p = 0; p < 4; p++)
#pragma unroll
            for (int m = 0; m < 8; m++) accp[th][p][m] = (f2){0.f, 0.f};

    for (int cc = 0; cc < 8; cc++) {
        __syncthreads();
        for (int e = tid; e < 1728; e += 256) {
            int ci = e & 15, r = e >> 4;          // r 0..107
            int tt = r / 3, mg = r - tt * 3;
            int gt = t0 + tt - 2;
            float4 v = {0.f, 0.f, 0.f, 0.f};
            if (gt >= 0 && gt < 1024) {
                const float* src = &X1[(((long)(b * 1024 + gt)) * 8) * 128 + cc * 16 + ci];
                float* pv = (float*)&v;
#pragma unroll
                for (int k2 = 0; k2 < 4; k2++) {
                    int gm = mg * 4 + k2 - 2;
                    if (gm >= 0 && gm < 8) pv[k2] = src[gm * 128];
                }
            }
            *(float4*)&xs[tt * 196 + ci * 12 + mg * 4] = v;
        }
        for (int dt = 0; dt < 5; dt++) {
            __syncthreads();
            for (int e = tid; e < 10240; e += 256) {
                int co = e & 127, ci = (e >> 7) & 15, dm = e >> 11;
                ws[dm * 2112 + ci * 132 + co] =
                    W2T[((dt * 5 + dm) * 128 + cc * 16 + ci) * 128 + co];
            }
            __syncthreads();
            for (int ci = 0; ci < 16; ci++) {
                f2 x2[2][6];
#pragma unroll
                for (int th = 0; th < 2; th++) {
                    const float* xp = &xs[(tp + th * 16 + dt) * 196 + ci * 12];
                    f4 a = *(const f4*)&xp[0];
                    f4 bv = *(const f4*)&xp[4];
                    f4 cv = *(const f4*)&xp[8];
                    x2[th][0] = (f2){a.x, a.y};   x2[th][1] = (f2){a.z, a.w};
                    x2[th][2] = (f2){bv.x, bv.y}; x2[th][3] = (f2){bv.z, bv.w};
                    x2[th][4] = (f2){cv.x, cv.y}; x2[th][5] = (f2){cv.z, cv.w};
                }
                const float* wb = &ws[ci * 132];
#pragma unroll
                for (int dm = 0; dm < 5; dm++) {
                    const float* wr = wb + dm * 2112;
                    f4 wa = *(const f4*)&wr[cog * 4];
                    f4 wbv = *(const f4*)&wr[64 + cog * 4];
                    f2 wp[4];
                    wp[0] = (f2){wa.x, wa.y};   wp[1] = (f2){wa.z, wa.w};
                    wp[2] = (f2){wbv.x, wbv.y}; wp[3] = (f2){wbv.z, wbv.w};
#pragma unroll
                    for (int th = 0; th < 2; th++)
#pragma unroll
                        for (int m = 0; m < 8; m++) {
                            const int j = m + dm;
                            f2 xpair = x2[th][j >> 1];
                            if (j & 1) {
                                PK_FMA_HI(accp[th][0][m], wp[0], xpair);
                                PK_FMA_HI(accp[th][1][m], wp[1], xpair);
                                PK_FMA_HI(accp[th][2][m], wp[2], xpair);
                                PK_FMA_HI(accp[th][3][m], wp[3], xpair);
                            } else {
                                PK_FMA_LO(accp[th][0][m], wp[0], xpair);
                                PK_FMA_LO(accp[th][1][m], wp[1], xpair);
                                PK_FMA_LO(accp[th][2][m], wp[2], xpair);
                                PK_FMA_LO(accp[th][3][m], wp[3], xpair);
                            }
                        }
                }
            }
        }
    }
#pragma unroll
    for (int th = 0; th < 2; th++) {
        int t = t0 + th * 16 + tp;
#pragma unroll
        for (int g = 0; g < 2; g++) {
            int cobase = g * 64 + cog * 4;
#pragma unroll
            for (int m2 = 0; m2 < 2; m2++) {
                float4 ov;
                float* po = (float*)&ov;
#pragma unroll
                for (int c = 0; c < 4; c++) {
                    float s = sc[cobase + c], h = sh[cobase + c];
                    float mx = 0.f;
#pragma unroll
                    for (int q = 0; q < 4; q++) {
                        f2 av = accp[th][g * 2 + (c >> 1)][m2 * 4 + q];
                        float a = (c & 1) ? av.y : av.x;
                        float y = fmaf(a, s, h);
                        y = fmaxf(y, 0.f);
                        mx = fmaxf(mx, y);
                    }
                    po[c] = mx;
                }
                *(float4*)&X2[(((long)(b * 1024 + t)) * 2 + m2) * 128 + cobase] = ov;
            }
        }
    }
}

// ------- conv3 (tap-pruned, conflict-free; validated R9: conflicts 6.5e8 -> 0) -------
__global__ __launch_bounds__(256) void k_conv3(
    const float* __restrict__ X2, const float* __restrict__ W3T,
    const float* __restrict__ bb, const float* __restrict__ gg,
    const float* __restrict__ be, const float* __restrict__ mm_,
    const float* __restrict__ vv, float* __restrict__ F)
{
    __shared__ __align__(16) float xs[20 * 66];     // [t''][ci*2+m], stride 66
    __shared__ __align__(16) float ws[3][32][64];   // [dm-1][ci][co]
    __shared__ float sc[64], sh[64];
    int bid = blockIdx.x;
    int coh = bid & 1, t0 = ((bid >> 1) & 63) << 4, b = bid >> 7;
    int co_base = coh * 64;
    int tid = threadIdx.x;
    int tp = tid & 15, cog = tid >> 4;
    if (tid < 64) {
        int co = co_base + tid;
        float s = gg[co] / sqrtf(vv[co] + EPSF);
        sc[tid] = s;
        sh[tid] = (bb[co] - mm_[co]) * s + be[co];
    }
    float acc[4][2];
#pragma unroll
    for (int c = 0; c < 4; c++) { acc[c][0] = 0.f; acc[c][1] = 0.f; }

    for (int cc = 0; cc < 4; cc++) {
        __syncthreads();
        for (int e = tid; e < 20 * 64; e += 256) {
            int tt = e >> 6, r = e & 63;
            int ci = r >> 1, m = r & 1;
            int gt = t0 + tt - 2;
            float v = 0.f;
            if (gt >= 0 && gt < 1024)
                v = X2[(((long)(b * 1024 + gt)) * 2 + m) * 128 + cc * 32 + ci];
            xs[tt * 66 + ci * 2 + m] = v;
        }
        for (int dt = 0; dt < 5; dt++) {
            __syncthreads();
            for (int e = tid; e < 3 * 32 * 64; e += 256) {
                int co = e & 63, ci = (e >> 6) & 31, dmi = e >> 11;
                ws[dmi][ci][co] = W3T[((dt * 5 + dmi + 1) * 128 + cc * 32 + ci) * 128 + co_base + co];
            }
            __syncthreads();
            for (int ci = 0; ci < 32; ci++) {
                float2 x = *(const float2*)&xs[(tp + dt) * 66 + ci * 2];
                float w1[4], w2[4], w3[4];
                *(float4*)w1 = *(const float4*)&ws[0][ci][cog * 4];
                *(float4*)w2 = *(const float4*)&ws[1][ci][cog * 4];
                *(float4*)w3 = *(const float4*)&ws[2][ci][cog * 4];
#pragma unroll
                for (int c = 0; c < 4; c++) acc[c][0] = fmaf(w2[c], x.x, acc[c][0]);
#pragma unroll
                for (int c = 0; c < 4; c++) acc[c][0] = fmaf(w3[c], x.y, acc[c][0]);
#pragma unroll
                for (int c = 0; c < 4; c++) acc[c][1] = fmaf(w1[c], x.x, acc[c][1]);
#pragma unroll
                for (int c = 0; c < 4; c++) acc[c][1] = fmaf(w2[c], x.y, acc[c][1]);
            }
        }
    }
    float4 ov;
    float* po = (float*)&ov;
#pragma unroll
    for (int c = 0; c < 4; c++) {
        float s = sc[cog * 4 + c], h = sh[cog * 4 + c];
        float y0 = fmaxf(fmaf(acc[c][0], s, h), 0.f);
        float y1 = fmaxf(fmaf(acc[c][1], s, h), 0.f);
        po[c] = fmaxf(y0, y1);
    }
    *(float4*)&F[((long)(t0 + tp) * 32 + b) * 128 + co_base + cog * 4] = ov;
}

// ---------------- Gx = F @ Wihx.T + bih : [32768,128]x[128,768] ----------------
__global__ __launch_bounds__(256) void k_gemm(
    const float* __restrict__ F, const float* __restrict__ WxT,
    const float* __restrict__ bih, float* __restrict__ Gx)
{
    __shared__ __align__(16) float Fs[64][33];
    __shared__ __align__(16) float Ws[32][256];
    int bid = blockIdx.x;
    int jt = bid % 3, tb0 = (bid / 3) * 64;
    int tid = threadIdx.x;
    int tx = tid & 31, ty = tid >> 5;
    float acc[8][8];
#pragma unroll
    for (int i = 0; i < 8; i++)
#pragma unroll
        for (int j = 0; j < 8; j++) acc[i][j] = 0.f;
    for (int cc = 0; cc < 4; cc++) {
        __syncthreads();
        for (int e = tid; e < 64 * 32; e += 256) {
            int ci = e & 31, i = e >> 5;
            Fs[i][ci] = F[(long)(tb0 + i) * 128 + cc * 32 + ci];
        }
        for (int e = tid; e < 32 * 256; e += 256) {
            int jj = e & 255, ci = e >> 8;
            Ws[ci][jj] = WxT[(cc * 32 + ci) * 768 + jt * 256 + jj];
        }
        __syncthreads();
        for (int ci = 0; ci < 32; ci++) {
            float a[8], w[8];
#pragma unroll
            for (int i = 0; i < 8; i++) a[i] = Fs[ty * 8 + i][ci];
            *(float4*)&w[0] = *(const float4*)&Ws[ci][tx * 8];
            *(float4*)&w[4] = *(const float4*)&Ws[ci][tx * 8 + 4];
#pragma unroll
            for (int i = 0; i < 8; i++)
#pragma unroll
                for (int j = 0; j < 8; j++) acc[i][j] = fmaf(a[i], w[j], acc[i][j]);
        }
    }
    float bj[8];
#pragma unroll
    for (int j = 0; j < 8; j++) bj[j] = bih[jt * 256 + tx * 8 + j];
#pragma unroll
    for (int i = 0; i < 8; i++) {
        float o[8];
#pragma unroll
        for (int j = 0; j < 8; j++) o[j] = acc[i][j] + bj[j];
        float* dst = &Gx[(long)(tb0 + ty * 8 + i) * 768 + jt * 256 + tx * 8];
        *(float4*)&dst[0] = *(float4*)&o[0];
        *(float4*)&dst[4] = *(float4*)&o[4];
    }
}

// ====== GRU v7: register-resident Whh, 1024 threads / 96 weight-VGPRs ======
// R2 post-mortem: waves_per_eu(2,2)+launch_bounds(512,2) did NOT raise the
// budget (VGPR_Count stayed 128) -> weights still round-tripped through the
// AGPR half / scratch. Fix: fit the 128-reg budget the compiler provably
// picks. 1024 threads = 64 groups x 16 lanes; group owns 12 rows; lane holds
// 12x16 = 192 fp16 = 96 VGPRs. Peak live ~127 <= 128 (h read per-p4, 4 regs
// not 16). waves_per_eu(4,4) pins min=max (16 waves/block forces 4/SIMD
// anyway). Numerics identical to v5/v6 (same 16-lane x 16-dim row dots, same
// reduce tree). WfL padded to stride 20/seg: proj f4 reads were the residual
// 4.5e6 bank conflicts (quad (4*seg)%8 in {0,4} -> 32 lanes/quad).
__global__ __attribute__((amdgpu_waves_per_eu(4, 4))) __launch_bounds__(1024) void k_gru2(
    const u32x4* __restrict__ Wp4, const float* __restrict__ Gx,
    const float* __restrict__ Wih, const float* __restrict__ bhh_g,
    const float* __restrict__ Wf, const float* __restrict__ bf_g,
    const float* __restrict__ targets, const unsigned char* __restrict__ fmask,
    const int* __restrict__ flag, float* __restrict__ out)
{
    __shared__ __align__(16) float hq[320];      // swizzled: HQ(d) = d + (d>>4)*4
    __shared__ __align__(16) float gsum[768];
    __shared__ float tfl[16];
    __shared__ float bhL[768];
    __shared__ __align__(16) float wtfL[7680];   // [cp(30)][256], cp = gate*10 + c
    __shared__ __align__(16) float WfL[3200];    // [oc(10)][seg(16)*20], padded
    const int b = blockIdx.x, tid = threadIdx.x;
    const int l = tid & 15, g = tid >> 4;        // g 0..63: rows g*12..+12
    const bool isGate = (tid < 256);
    const bool isProj = (tid >= 256 && tid < 416);
    const int oc = (tid - 256) >> 4, seg = tid & 15;
    const bool isWr = isProj && (seg == 15);

    // ---- load register-resident weights: 24 x dwordx4, coalesced ----
    u32x4 w4[24];
#pragma unroll
    for (int q = 0; q < 24; q++) w4[q] = Wp4[q * 1024 + tid];

    // ---- one-time LDS fills ----
    for (int e = tid; e < 7680; e += 1024) {
        int cp = e >> 8, jj = e & 255;
        int gg = cp / 10, c = cp - gg * 10;
        wtfL[e] = Wih[(gg * 256 + jj) * 138 + 128 + c];
    }
    for (int e = tid; e < 3200; e += 1024) {
        int oo = e / 320, rem = e - oo * 320;
        int sg = rem / 20, ii = rem - sg * 20;
        WfL[e] = (ii < 16) ? Wf[oo * 256 + sg * 16 + ii] : 0.f;
    }
    if (tid < 768) bhL[tid] = bhh_g[tid];
    if (tid < 320) hq[tid] = 0.f;
    if (tid < 16) tfl[tid] = 0.f;
    float bfc = isProj ? bf_g[oc] : 0.f;
    const int int32mode = flag[0];
    const float* hb = &hq[l * 20];               // lane's swizzled h base
    __syncthreads();

    for (int t = 0; t < 1024; t++) {
        // issue per-step global loads early; consumed after B1 (latency
        // hidden under the matvec)
        float gxr = 0.f, gxz = 0.f, gxn = 0.f;
        if (isGate) {
            const float* gx = &Gx[((long)t * 32 + b) * 768];
            gxr = gx[tid]; gxz = gx[tid + 256]; gxn = gx[tid + 512];
        }
        float tgt = 0.f; int fmv = 0;
        if (isWr) {
            tgt = targets[((long)b * 1024 + t) * 10 + oc];
            fmv = int32mode ? ((const int*)fmask)[t * 32 + b] : (int)fmask[t * 32 + b];
        }

        // ---- matvec: acc[r] += Whh[g*12+r][l*16+k] * h[l*16+k], k=0..15 ----
        float acc[12];
#pragma unroll
        for (int r = 0; r < 12; r++) acc[r] = 0.f;
#pragma unroll
        for (int p4 = 0; p4 < 4; p4++) {
            f4 hv = *(const f4*)&hb[p4 * 4];
#pragma unroll
            for (int r = 0; r < 12; r++) {
                unsigned int wa = w4[r * 2 + (p4 >> 1)][(p4 & 1) * 2];
                unsigned int wb = w4[r * 2 + (p4 >> 1)][(p4 & 1) * 2 + 1];
                FMA_MIX_LO(acc[r], wa, hv.x);
                FMA_MIX_HI(acc[r], wa, hv.y);
                FMA_MIX_LO(acc[r], wb, hv.z);
                FMA_MIX_HI(acc[r], wb, hv.w);
            }
        }
        // ---- 16-lane reduce; lane 15 of each group holds full row sums ----
#pragma unroll
        for (int r = 0; r < 12; r++) {
            float s = acc[r];
            s = dpp_add<0x111>(s);
            s = dpp_add<0x112>(s);
            s = dpp_add<0x114>(s);
            s = dpp_add<0x118>(s);
            acc[r] = s;
        }
        if (l == 15) {
#pragma unroll
            for (int r = 0; r < 12; r++) gsum[g * 12 + r] = acc[r];
        }
        __syncthreads();   // B1: gsum ready; h reads of step t complete

        if (isGate) {
            float hold = hq[HQ(tid)];
            float gr = gxr, gz = gxz, gn = gxn;
#pragma unroll
            for (int c = 0; c < 10; c++) {
                float tv = tfl[c];
                gr = fmaf(tv, wtfL[c * 256 + tid], gr);
                gz = fmaf(tv, wtfL[(10 + c) * 256 + tid], gz);
                gn = fmaf(tv, wtfL[(20 + c) * 256 + tid], gn);
            }
            float ar = gsum[tid] + bhL[tid];
            float az = gsum[tid + 256] + bhL[tid + 256];
            float an = gsum[tid + 512] + bhL[tid + 512];
            float r = 1.0f / (1.0f + expf(-(gr + ar)));
            float z = 1.0f / (1.0f + expf(-(gz + az)));
            float n = tanhf(fmaf(r, an, gn));
            float hnew = (1.0f - z) * n + z * hold;
            hq[HQ(tid)] = hnew;
        }
        __syncthreads();   // B2: h ready

        if (isProj) {
            float s = 0.f;
#pragma unroll
            for (int qq = 0; qq < 4; qq++) {
                f4 h4 = *(const f4*)&hq[seg * 20 + qq * 4];
                f4 wv = *(const f4*)&WfL[oc * 320 + seg * 20 + qq * 4];
                s = fmaf(wv.x, h4.x, s);
                s = fmaf(wv.y, h4.y, s);
                s = fmaf(wv.z, h4.z, s);
                s = fmaf(wv.w, h4.w, s);
            }
            s = dpp_add<0x111>(s);
            s = dpp_add<0x112>(s);
            s = dpp_add<0x114>(s);
            s = dpp_add<0x118>(s);
            if (isWr) {
                float o = s + bfc;
                out[((long)b * 1024 + t) * 10 + oc] = o;
                float pred = (o > 0.f) ? 1.f : 0.f;
                tfl[oc] = fmv ? tgt : pred;
            }
        }
        // no extra barrier: proj's hq/tfl accesses sit between B2(t) and
        // B1(t+1); gates touch them only after B1(t+1).
    }
}

extern "C" void kernel_launch(void* const* d_in, const int* in_sizes, int n_in,
                              void* d_out, int out_size, void* d_ws, size_t ws_size,
                              hipStream_t stream) {
    (void)in_sizes; (void)n_in; (void)out_size; (void)ws_size;
    const float* features = (const float*)d_in[0];
    const float* targets  = (const float*)d_in[1];
    const unsigned char* fmask = (const unsigned char*)d_in[2];
    const float* W1  = (const float*)d_in[3];
    const float* b1  = (const float*)d_in[4];
    const float* g1  = (const float*)d_in[5];
    const float* be1 = (const float*)d_in[6];
    const float* m1  = (const float*)d_in[7];
    const float* v1  = (const float*)d_in[8];
    const float* W2  = (const float*)d_in[9];
    const float* b2  = (const float*)d_in[10];
    const float* g2  = (const float*)d_in[11];
    const float* be2 = (const float*)d_in[12];
    const float* m2  = (const float*)d_in[13];
    const float* v2  = (const float*)d_in[14];
    const float* W3  = (const float*)d_in[15];
    const float* b3  = (const float*)d_in[16];
    const float* g3  = (const float*)d_in[17];
    const float* be3 = (const float*)d_in[18];
    const float* m3  = (const float*)d_in[19];
    const float* v3  = (const float*)d_in[20];
    const float* Wih = (const float*)d_in[21];
    const float* Whh = (const float*)d_in[22];
    const float* bih = (const float*)d_in[23];
    const float* bhh = (const float*)d_in[24];
    const float* Wf  = (const float*)d_in[25];
    const float* bf  = (const float*)d_in[26];

    char* w = (char*)d_ws;
    unsigned int* WhhP = (unsigned int*)(w + 0);        // 393216 B (in 786432 slot)
    float* WxT = (float*)(w + 786432);                  // 393216 B
    float* W2T = (float*)(w + 1179648);                 // 1638400 B
    float* W3T = (float*)(w + 2818048);                 // 1638400 B
    int*   flag = (int*)(w + 4456448);                  // 512 B slot
    float* X1  = (float*)(w + 4456960);                 // 128 MB; reused as Gx after conv2
    float* Gx  = X1;
    float* X2  = (float*)(w + 4456960 + 134217728);     // 32 MB
    float* F   = (float*)(w + 4456960 + 134217728 + 33554432); // 16 MB
    float* out = (float*)d_out;

    k_prep<<<1600, 256, 0, stream>>>(Wih, Whh, W2, W3, fmask, WhhP, WxT, W2T, W3T, flag);
    k_conv1<<<8192, 256, 0, stream>>>(features, W1, b1, g1, be1, m1, v1, X1);
    k_conv2<<<1024, 256, 0, stream>>>(X1, W2T, b2, g2, be2, m2, v2, X2);
    k_conv3<<<4096, 256, 0, stream>>>(X2, W3T, b3, g3, be3, m3, v3, F);
    k_gemm<<<1536, 256, 0, stream>>>(F, WxT, bih, Gx);
    k_gru2<<<32, 1024, 0, stream>>>((const u32x4*)WhhP, Gx, Wih, bhh, Wf, bf,
                                    targets, fmask, flag, out);
}

// Round 4
// 6354.411 us; speedup vs baseline: 1.2205x; 1.2205x over previous
//
#include <hip/hip_runtime.h>
#include <math.h>

#define EPSF 1e-5f

typedef __attribute__((ext_vector_type(2))) float f2;
typedef __attribute__((ext_vector_type(4))) float f4;
typedef __attribute__((ext_vector_type(8))) _Float16 h8;
typedef __attribute__((ext_vector_type(4))) unsigned int u32x4;

// packed fp32 FMA with x broadcast via op_sel (lo or hi half of the x pair)
#define PK_FMA_LO(ACC, W, X) \
    asm("v_pk_fma_f32 %0, %1, %2, %0 op_sel:[0,0,0] op_sel_hi:[1,0,1]" \
        : "+v"(ACC) : "v"(W), "v"(X))
#define PK_FMA_HI(ACC, W, X) \
    asm("v_pk_fma_f32 %0, %1, %2, %0 op_sel:[0,1,0] op_sel_hi:[1,1,1]" \
        : "+v"(ACC) : "v"(W), "v"(X))

// mixed-precision FMA: fp32 acc += fp16(half of W) * fp32 H
#define FMA_MIX_LO(ACC, W, H) \
    asm("v_fma_mix_f32 %0, %1, %2, %0 op_sel:[0,0,0] op_sel_hi:[1,0,0]" \
        : "+v"(ACC) : "v"(W), "v"(H))
#define FMA_MIX_HI(ACC, W, H) \
    asm("v_fma_mix_f32 %0, %1, %2, %0 op_sel:[1,0,0] op_sel_hi:[1,0,0]" \
        : "+v"(ACC) : "v"(W), "v"(H))

// DPP helper: v += value from lane (i - N) within the 16-lane DPP row (0 if OOB)
template<int CTRL>
__device__ __forceinline__ float dpp_add(float v) {
    int s = __builtin_amdgcn_update_dpp(0, __float_as_int(v), CTRL, 0xf, 0xf, true);
    return v + __int_as_float(s);
}

// hq swizzle: +4 floats of pad per 16 (stride 20)
#define HQ(d) ((d) + (((d) >> 4) << 2))

// ---------------- prep: weight transposes + bool-dtype detect ----------------
// WhhP: per-thread register layout for k_gru2 (512 threads, R2 layout).
//   thread tid: group g=tid>>4 owns rows g*24..+24; lane l=tid&15 owns dims l*16..+16.
//   u32 idx = (q*512 + tid)*4 + j, pair pp=q*4+j (0..191), r=pp>>3, p=pp&7.
__global__ __launch_bounds__(256) void k_prep(
    const float* __restrict__ Wih, const float* __restrict__ Whh,
    const float* __restrict__ W2, const float* __restrict__ W3,
    const unsigned char* __restrict__ fmask,
    unsigned int* __restrict__ WhhP, float* __restrict__ WxT,
    float* __restrict__ W2T, float* __restrict__ W3T, int* __restrict__ flag)
{
    int idx = blockIdx.x * 256 + threadIdx.x;
    if (idx < 98304) {                  // Whh -> register-resident layout (512-thr)
        int q = idx >> 11;
        int rem = idx & 2047;
        int ttid = rem >> 2, j3 = idx & 3;
        int pp = q * 4 + j3;
        int r = pp >> 3, p = pp & 7;
        int row = (ttid >> 4) * 24 + r;
        int col = (ttid & 15) * 16 + p * 2;
        union { _Float16 h[2]; unsigned int u; } pk;
        pk.h[0] = (_Float16)Whh[row * 256 + col];
        pk.h[1] = (_Float16)Whh[row * 256 + col + 1];
        WhhP[idx] = pk.u;
    }
    if (idx < 105984) {                 // Wih[768][138] x-part -> WxT[128][768]
        int j = idx / 138, k = idx % 138;
        if (k < 128) WxT[k * 768 + j] = Wih[idx];
    }
    if (idx < 409600) {                 // W[co][ci][5][5] -> WT[tap][ci][co]
        int co = idx / 3200, r = idx % 3200;
        int ci = r / 25, tap = r % 25;
        int dst = (tap * 128 + ci) * 128 + co;
        W2T[dst] = W2[idx];
        W3T[dst] = W3[idx];
    }
    if (idx == 0) {                     // bool stored as int32?
        int nz = 0;
        for (int i = 0; i < 4096; i++) if ((i & 3) != 0) nz |= fmask[i];
        *flag = nz ? 0 : 1;
    }
}

// ---------------- conv1: [32,1,1024,40] -> X1[b][t][m1(8)][co(128)] ----------------
__global__ __launch_bounds__(256) void k_conv1(
    const float* __restrict__ X, const float* __restrict__ W1,
    const float* __restrict__ bb, const float* __restrict__ gg,
    const float* __restrict__ be, const float* __restrict__ mm_,
    const float* __restrict__ vv, float* __restrict__ X1)
{
    __shared__ __align__(16) float xs[8][44];
    __shared__ __align__(16) float ws[25][128];
    __shared__ float sc[128], sh[128];
    int bid = blockIdx.x;
    int b = bid >> 8, t0 = (bid & 255) << 2;
    int tid = threadIdx.x;
    for (int e = tid; e < 8 * 44; e += 256) {
        int tt = e / 44, mm = e % 44;
        int gt = t0 + tt - 2, gm = mm - 2;
        float val = 0.f;
        if (gt >= 0 && gt < 1024 && gm >= 0 && gm < 40)
            val = X[(b * 1024 + gt) * 40 + gm];
        xs[tt][mm] = val;
    }
    for (int e = tid; e < 3200; e += 256) {
        int tap = e >> 7, co = e & 127;
        ws[tap][co] = W1[co * 25 + tap];
    }
    if (tid < 128) {
        float s = gg[tid] / sqrtf(vv[tid] + EPSF);
        sc[tid] = s;
        sh[tid] = (bb[tid] - mm_[tid]) * s + be[tid];
    }
    __syncthreads();
    int cog = tid >> 5;          // 8 groups x 16 co
    int m1i = (tid >> 2) & 7;    // pooled mel
    int tp  = tid & 3;           // t'
    int co0 = cog * 16;
    float val[5][16];
#pragma unroll
    for (int p = 0; p < 5; p++)
#pragma unroll
        for (int i = 0; i < 16; i++) val[p][i] = 0.f;
#pragma unroll
    for (int dt = 0; dt < 5; dt++) {
#pragma unroll
        for (int dm = 0; dm < 5; dm++) {
            float w[16];
#pragma unroll
            for (int i = 0; i < 16; i += 4)
                *(float4*)&w[i] = *(const float4*)&ws[dt * 5 + dm][co0 + i];
#pragma unroll
            for (int p = 0; p < 5; p++) {
                float x = xs[tp + dt][m1i * 5 + p + dm];
#pragma unroll
                for (int i = 0; i < 16; i++) val[p][i] = fmaf(x, w[i], val[p][i]);
            }
        }
    }
    float outv[16];
#pragma unroll
    for (int i = 0; i < 16; i++) {
        float s = sc[co0 + i], h = sh[co0 + i];
        float mx = 0.f;
#pragma unroll
        for (int p = 0; p < 5; p++) {
            float y = fmaf(val[p][i], s, h);
            y = fmaxf(y, 0.f);
            mx = fmaxf(mx, y);
        }
        outv[i] = mx;
    }
    float* dst = &X1[(((long)(b * 1024 + t0 + tp)) * 8 + m1i) * 128 + co0];
#pragma unroll
    for (int i = 0; i < 16; i += 4) *(float4*)&dst[i] = *(float4*)&outv[i];
}

// -------- conv2 v5: ci-chunk 8, LDS 36KB -> 4 blocks/CU (was 2) --------
// R3 analysis: VALUBusy 64%, Occupancy 18.7% -- barrier/latency stalls with
// only 2 blocks/CU (71KB LDS + waves_per_eu pin). Same instruction stream,
// half the LDS: xs[36][100] (8 ci), ws[5][8][128], cc loop 8->16.
__global__ __launch_bounds__(256) void k_conv2(
    const float* __restrict__ X1, const float* __restrict__ W2T,
    const float* __restrict__ bb, const float* __restrict__ gg,
    const float* __restrict__ be, const float* __restrict__ mm_,
    const float* __restrict__ vv, float* __restrict__ X2)
{
    __shared__ __align__(16) float xs[36 * 100];    // [tt][ci*12 + m], ci<8
    __shared__ __align__(16) float ws[5 * 8 * 128]; // [dm][ci][co]
    __shared__ float sc[128], sh[128];
    int bid = blockIdx.x;
    int t0 = (bid & 31) << 5, b = bid >> 5;
    int tid = threadIdx.x;
    int tp = tid & 15, cog = tid >> 4;
    if (tid < 128) {
        float s = gg[tid] / sqrtf(vv[tid] + EPSF);
        sc[tid] = s;
        sh[tid] = (bb[tid] - mm_[tid]) * s + be[tid];
    }
    f2 accp[2][4][8];                    // [t-half][co pair][m]
#pragma unroll
    for (int th = 0; th < 2; th++)
#pragma unroll
        for (int p = 0; p < 4; p++)
#pragma unroll
            for (int m = 0; m < 8; m++) accp[th][p][m] = (f2){0.f, 0.f};

    for (int cc = 0; cc < 16; cc++) {
        __syncthreads();
        for (int e = tid; e < 864; e += 256) {
            int ci = e & 7, r = e >> 3;           // r 0..107
            int tt = r / 3, mg = r - tt * 3;
            int gt = t0 + tt - 2;
            float4 v = {0.f, 0.f, 0.f, 0.f};
            if (gt >= 0 && gt < 1024) {
                const float* src = &X1[(((long)(b * 1024 + gt)) * 8) * 128 + cc * 8 + ci];
                float* pv = (float*)&v;
#pragma unroll
                for (int k2 = 0; k2 < 4; k2++) {
                    int gm = mg * 4 + k2 - 2;
                    if (gm >= 0 && gm < 8) pv[k2] = src[gm * 128];
                }
            }
            *(float4*)&xs[tt * 100 + ci * 12 + mg * 4] = v;
        }
        for (int dt = 0; dt < 5; dt++) {
            __syncthreads();
            for (int e = tid; e < 5120; e += 256) {
                int co = e & 127, ci = (e >> 7) & 7, dm = e >> 10;
                ws[dm * 1024 + ci * 128 + co] =
                    W2T[((dt * 5 + dm) * 128 + cc * 8 + ci) * 128 + co];
            }
            __syncthreads();
            for (int ci = 0; ci < 8; ci++) {
                f2 x2[2][6];
#pragma unroll
                for (int th = 0; th < 2; th++) {
                    const float* xp = &xs[(tp + th * 16 + dt) * 100 + ci * 12];
                    f4 a = *(const f4*)&xp[0];
                    f4 bv = *(const f4*)&xp[4];
                    f4 cv = *(const f4*)&xp[8];
                    x2[th][0] = (f2){a.x, a.y};   x2[th][1] = (f2){a.z, a.w};
                    x2[th][2] = (f2){bv.x, bv.y}; x2[th][3] = (f2){bv.z, bv.w};
                    x2[th][4] = (f2){cv.x, cv.y}; x2[th][5] = (f2){cv.z, cv.w};
                }
                const float* wb = &ws[ci * 128];
#pragma unroll
                for (int dm = 0; dm < 5; dm++) {
                    const float* wr = wb + dm * 1024;
                    f4 wa = *(const f4*)&wr[cog * 4];
                    f4 wbv = *(const f4*)&wr[64 + cog * 4];
                    f2 wp[4];
                    wp[0] = (f2){wa.x, wa.y};   wp[1] = (f2){wa.z, wa.w};
                    wp[2] = (f2){wbv.x, wbv.y}; wp[3] = (f2){wbv.z, wbv.w};
#pragma unroll
                    for (int th = 0; th < 2; th++)
#pragma unroll
                        for (int m = 0; m < 8; m++) {
                            const int j = m + dm;
                            f2 xpair = x2[th][j >> 1];
                            if (j & 1) {
                                PK_FMA_HI(accp[th][0][m], wp[0], xpair);
                                PK_FMA_HI(accp[th][1][m], wp[1], xpair);
                                PK_FMA_HI(accp[th][2][m], wp[2], xpair);
                                PK_FMA_HI(accp[th][3][m], wp[3], xpair);
                            } else {
                                PK_FMA_LO(accp[th][0][m], wp[0], xpair);
                                PK_FMA_LO(accp[th][1][m], wp[1], xpair);
                                PK_FMA_LO(accp[th][2][m], wp[2], xpair);
                                PK_FMA_LO(accp[th][3][m], wp[3], xpair);
                            }
                        }
                }
            }
        }
    }
#pragma unroll
    for (int th = 0; th < 2; th++) {
        int t = t0 + th * 16 + tp;
#pragma unroll
        for (int g = 0; g < 2; g++) {
            int cobase = g * 64 + cog * 4;
#pragma unroll
            for (int m2 = 0; m2 < 2; m2++) {
                float4 ov;
                float* po = (float*)&ov;
#pragma unroll
                for (int c = 0; c < 4; c++) {
                    float s = sc[cobase + c], h = sh[cobase + c];
                    float mx = 0.f;
#pragma unroll
                    for (int q = 0; q < 4; q++) {
                        f2 av = accp[th][g * 2 + (c >> 1)][m2 * 4 + q];
                        float a = (c & 1) ? av.y : av.x;
                        float y = fmaf(a, s, h);
                        y = fmaxf(y, 0.f);
                        mx = fmaxf(mx, y);
                    }
                    po[c] = mx;
                }
                *(float4*)&X2[(((long)(b * 1024 + t)) * 2 + m2) * 128 + cobase] = ov;
            }
        }
    }
}

// ------- conv3 v2: t-tile 64 (was 16) -> ws staging amortized 4x -------
// R3 analysis: VALUBusy 31% -- staging-latency-bound (24 global loads per
// 512 FMA per stage-iter, restaged 20x/block). Now 2048 FMA per stage-iter.
__global__ __launch_bounds__(256) void k_conv3(
    const float* __restrict__ X2, const float* __restrict__ W3T,
    const float* __restrict__ bb, const float* __restrict__ gg,
    const float* __restrict__ be, const float* __restrict__ mm_,
    const float* __restrict__ vv, float* __restrict__ F)
{
    __shared__ __align__(16) float xs[68 * 66];     // [t''][ci*2+m], stride 66
    __shared__ __align__(16) float ws[3][32][64];   // [dm-1][ci][co]
    __shared__ float sc[64], sh[64];
    int bid = blockIdx.x;
    int coh = bid & 1, t0 = ((bid >> 1) & 15) << 6, b = bid >> 5;
    int co_base = coh * 64;
    int tid = threadIdx.x;
    int tp = tid & 15, cog = tid >> 4;
    if (tid < 64) {
        int co = co_base + tid;
        float s = gg[co] / sqrtf(vv[co] + EPSF);
        sc[tid] = s;
        sh[tid] = (bb[co] - mm_[co]) * s + be[co];
    }
    float acc[4][4][2];                              // [t-chunk][c][pos]
#pragma unroll
    for (int tc = 0; tc < 4; tc++)
#pragma unroll
        for (int c = 0; c < 4; c++) { acc[tc][c][0] = 0.f; acc[tc][c][1] = 0.f; }

    for (int cc = 0; cc < 4; cc++) {
        __syncthreads();
        for (int e = tid; e < 68 * 64; e += 256) {
            int tt = e >> 6, r = e & 63;
            int ci = r >> 1, m = r & 1;
            int gt = t0 + tt - 2;
            float v = 0.f;
            if (gt >= 0 && gt < 1024)
                v = X2[(((long)(b * 1024 + gt)) * 2 + m) * 128 + cc * 32 + ci];
            xs[tt * 66 + ci * 2 + m] = v;
        }
        for (int dt = 0; dt < 5; dt++) {
            __syncthreads();
            for (int e = tid; e < 3 * 32 * 64; e += 256) {
                int co = e & 63, ci = (e >> 6) & 31, dmi = e >> 11;
                ws[dmi][ci][co] = W3T[((dt * 5 + dmi + 1) * 128 + cc * 32 + ci) * 128 + co_base + co];
            }
            __syncthreads();
            for (int ci = 0; ci < 32; ci++) {
                float w1[4], w2[4], w3[4];
                *(float4*)w1 = *(const float4*)&ws[0][ci][cog * 4];
                *(float4*)w2 = *(const float4*)&ws[1][ci][cog * 4];
                *(float4*)w3 = *(const float4*)&ws[2][ci][cog * 4];
#pragma unroll
                for (int tc = 0; tc < 4; tc++) {
                    float2 x = *(const float2*)&xs[(tc * 16 + tp + dt) * 66 + ci * 2];
#pragma unroll
                    for (int c = 0; c < 4; c++) acc[tc][c][0] = fmaf(w2[c], x.x, acc[tc][c][0]);
#pragma unroll
                    for (int c = 0; c < 4; c++) acc[tc][c][0] = fmaf(w3[c], x.y, acc[tc][c][0]);
#pragma unroll
                    for (int c = 0; c < 4; c++) acc[tc][c][1] = fmaf(w1[c], x.x, acc[tc][c][1]);
#pragma unroll
                    for (int c = 0; c < 4; c++) acc[tc][c][1] = fmaf(w2[c], x.y, acc[tc][c][1]);
                }
            }
        }
    }
#pragma unroll
    for (int tc = 0; tc < 4; tc++) {
        float4 ov;
        float* po = (float*)&ov;
#pragma unroll
        for (int c = 0; c < 4; c++) {
            float s = sc[cog * 4 + c], h = sh[cog * 4 + c];
            float y0 = fmaxf(fmaf(acc[tc][c][0], s, h), 0.f);
            float y1 = fmaxf(fmaf(acc[tc][c][1], s, h), 0.f);
            po[c] = fmaxf(y0, y1);
        }
        *(float4*)&F[((long)(t0 + tc * 16 + tp) * 32 + b) * 128 + co_base + cog * 4] = ov;
    }
}

// ---------------- Gx = F @ Wihx.T + bih : [32768,128]x[128,768] ----------------
__global__ __launch_bounds__(256) void k_gemm(
    const float* __restrict__ F, const float* __restrict__ WxT,
    const float* __restrict__ bih, float* __restrict__ Gx)
{
    __shared__ __align__(16) float Fs[64][33];
    __shared__ __align__(16) float Ws[32][256];
    int bid = blockIdx.x;
    int jt = bid % 3, tb0 = (bid / 3) * 64;
    int tid = threadIdx.x;
    int tx = tid & 31, ty = tid >> 5;
    float acc[8][8];
#pragma unroll
    for (int i = 0; i < 8; i++)
#pragma unroll
        for (int j = 0; j < 8; j++) acc[i][j] = 0.f;
    for (int cc = 0; cc < 4; cc++) {
        __syncthreads();
        for (int e = tid; e < 64 * 32; e += 256) {
            int ci = e & 31, i = e >> 5;
            Fs[i][ci] = F[(long)(tb0 + i) * 128 + cc * 32 + ci];
        }
        for (int e = tid; e < 32 * 256; e += 256) {
            int jj = e & 255, ci = e >> 8;
            Ws[ci][jj] = WxT[(cc * 32 + ci) * 768 + jt * 256 + jj];
        }
        __syncthreads();
        for (int ci = 0; ci < 32; ci++) {
            float a[8], w[8];
#pragma unroll
            for (int i = 0; i < 8; i++) a[i] = Fs[ty * 8 + i][ci];
            *(float4*)&w[0] = *(const float4*)&Ws[ci][tx * 8];
            *(float4*)&w[4] = *(const float4*)&Ws[ci][tx * 8 + 4];
#pragma unroll
            for (int i = 0; i < 8; i++)
#pragma unroll
                for (int j = 0; j < 8; j++) acc[i][j] = fmaf(a[i], w[j], acc[i][j]);
        }
    }
    float bj[8];
#pragma unroll
    for (int j = 0; j < 8; j++) bj[j] = bih[jt * 256 + tx * 8 + j];
#pragma unroll
    for (int i = 0; i < 8; i++) {
        float o[8];
#pragma unroll
        for (int j = 0; j < 8; j++) o[j] = acc[i][j] + bj[j];
        float* dst = &Gx[(long)(tb0 + ty * 8 + i) * 768 + jt * 256 + tx * 8];
        *(float4*)&dst[0] = *(float4*)&o[0];
        *(float4*)&dst[4] = *(float4*)&o[4];
    }
}

// ====== GRU v6r: R2 config (best measured, 2837us) + WfL stride-20 pad ======
// R1-R3 post-mortems: the allocator refuses to keep >=96-dword weight arrays
// live across the 1024-step barrier loop (3 refusals here + 5 in the prior
// session). R2's config -- 512 thr, VGPR_Count 128, overflow weights
// L2-resident -- is the best reachable point of this structure. WfL pad
// removes the residual 4.5e6 proj-phase bank conflicts (R3-validated).
__global__ __attribute__((amdgpu_waves_per_eu(2, 2))) __launch_bounds__(512, 2) void k_gru2(
    const u32x4* __restrict__ Wp4, const float* __restrict__ Gx,
    const float* __restrict__ Wih, const float* __restrict__ bhh_g,
    const float* __restrict__ Wf, const float* __restrict__ bf_g,
    const float* __restrict__ targets, const unsigned char* __restrict__ fmask,
    const int* __restrict__ flag, float* __restrict__ out)
{
    __shared__ __align__(16) float hq[320];      // swizzled: HQ(d) = d + (d>>4)*4
    __shared__ __align__(16) float gsum[768];
    __shared__ float tfl[16];
    __shared__ float bhL[768];
    __shared__ __align__(16) float wtfL[7680];   // [cp(30)][256], cp = gate*10 + c
    __shared__ __align__(16) float WfL[3200];    // [oc(10)][seg(16)*20], padded
    const int b = blockIdx.x, tid = threadIdx.x;
    const int l = tid & 15, g = tid >> 4;
    const bool isGate = (tid < 256);
    const bool isProj = (tid >= 256 && tid < 416);
    const int oc = (tid - 256) >> 4, seg = tid & 15;
    const bool isWr = isProj && (seg == 15);

    // ---- load register-resident weights: 48 x dwordx4, coalesced ----
    u32x4 w4[48];
#pragma unroll
    for (int q = 0; q < 48; q++) w4[q] = Wp4[q * 512 + tid];

    // ---- one-time LDS fills ----
    for (int e = tid; e < 7680; e += 512) {
        int cp = e >> 8, jj = e & 255;
        int gg = cp / 10, c = cp - gg * 10;
        wtfL[e] = Wih[(gg * 256 + jj) * 138 + 128 + c];
    }
    for (int e = tid; e < 3200; e += 512) {
        int oo = e / 320, rem = e - oo * 320;
        int sg = rem / 20, ii = rem - sg * 20;
        WfL[e] = (ii < 16) ? Wf[oo * 256 + sg * 16 + ii] : 0.f;
    }
    for (int e = tid; e < 768; e += 512) bhL[e] = bhh_g[e];
    for (int e = tid; e < 320; e += 512) hq[e] = 0.f;
    if (tid < 16) tfl[tid] = 0.f;
    float bfc = isProj ? bf_g[oc] : 0.f;
    const int int32mode = flag[0];
    const float* hb = &hq[l * 20];               // lane's swizzled h base
    __syncthreads();

    for (int t = 0; t < 1024; t++) {
        float gxr = 0.f, gxz = 0.f, gxn = 0.f;
        if (isGate) {
            const float* gx = &Gx[((long)t * 32 + b) * 768];
            gxr = gx[tid]; gxz = gx[tid + 256]; gxn = gx[tid + 512];
        }
        float tgt = 0.f; int fmv = 0;
        if (isWr) {
            tgt = targets[((long)b * 1024 + t) * 10 + oc];
            fmv = int32mode ? ((const int*)fmask)[t * 32 + b] : (int)fmask[t * 32 + b];
        }

        // ---- matvec: acc[r] += Whh[g*24+r][l*16+k] * h[l*16+k], k=0..15 ----
        f4 hvv[4];
#pragma unroll
        for (int p4 = 0; p4 < 4; p4++) hvv[p4] = *(const f4*)&hb[p4 * 4];
        float acc[24];
#pragma unroll
        for (int r = 0; r < 24; r++) acc[r] = 0.f;
#pragma unroll
        for (int p4 = 0; p4 < 4; p4++) {
            f4 hv = hvv[p4];
#pragma unroll
            for (int r = 0; r < 24; r++) {
                unsigned int wa = w4[r * 2 + (p4 >> 1)][(p4 & 1) * 2];
                unsigned int wb = w4[r * 2 + (p4 >> 1)][(p4 & 1) * 2 + 1];
                FMA_MIX_LO(acc[r], wa, hv.x);
                FMA_MIX_HI(acc[r], wa, hv.y);
                FMA_MIX_LO(acc[r], wb, hv.z);
                FMA_MIX_HI(acc[r], wb, hv.w);
            }
        }
        // ---- 16-lane reduce; lane 15 of each group holds full row sums ----
#pragma unroll
        for (int r = 0; r < 24; r++) {
            float s = acc[r];
            s = dpp_add<0x111>(s);
            s = dpp_add<0x112>(s);
            s = dpp_add<0x114>(s);
            s = dpp_add<0x118>(s);
            acc[r] = s;
        }
        if (l == 15) {
#pragma unroll
            for (int r = 0; r < 24; r++) gsum[g * 24 + r] = acc[r];
        }
        __syncthreads();   // B1: gsum ready; h reads of step t complete

        if (isGate) {
            float hold = hq[HQ(tid)];
            float gr = gxr, gz = gxz, gn = gxn;
#pragma unroll
            for (int c = 0; c < 10; c++) {
                float tv = tfl[c];
                gr = fmaf(tv, wtfL[c * 256 + tid], gr);
                gz = fmaf(tv, wtfL[(10 + c) * 256 + tid], gz);
                gn = fmaf(tv, wtfL[(20 + c) * 256 + tid], gn);
            }
            float ar = gsum[tid] + bhL[tid];
            float az = gsum[tid + 256] + bhL[tid + 256];
            float an = gsum[tid + 512] + bhL[tid + 512];
            float r = 1.0f / (1.0f + expf(-(gr + ar)));
            float z = 1.0f / (1.0f + expf(-(gz + az)));
            float n = tanhf(fmaf(r, an, gn));
            float hnew = (1.0f - z) * n + z * hold;
            hq[HQ(tid)] = hnew;
        }
        __syncthreads();   // B2: h ready

        if (isProj) {
            float s = 0.f;
#pragma unroll
            for (int qq = 0; qq < 4; qq++) {
                f4 h4 = *(const f4*)&hq[seg * 20 + qq * 4];
                f4 wv = *(const f4*)&WfL[oc * 320 + seg * 20 + qq * 4];
                s = fmaf(wv.x, h4.x, s);
                s = fmaf(wv.y, h4.y, s);
                s = fmaf(wv.z, h4.z, s);
                s = fmaf(wv.w, h4.w, s);
            }
            s = dpp_add<0x111>(s);
            s = dpp_add<0x112>(s);
            s = dpp_add<0x114>(s);
            s = dpp_add<0x118>(s);
            if (isWr) {
                float o = s + bfc;
                out[((long)b * 1024 + t) * 10 + oc] = o;
                float pred = (o > 0.f) ? 1.f : 0.f;
                tfl[oc] = fmv ? tgt : pred;
            }
        }
        // no extra barrier: proj's hq/tfl accesses sit between B2(t) and
        // B1(t+1); gates touch them only after B1(t+1).
    }
}

extern "C" void kernel_launch(void* const* d_in, const int* in_sizes, int n_in,
                              void* d_out, int out_size, void* d_ws, size_t ws_size,
                              hipStream_t stream) {
    (void)in_sizes; (void)n_in; (void)out_size; (void)ws_size;
    const float* features = (const float*)d_in[0];
    const float* targets  = (const float*)d_in[1];
    const unsigned char* fmask = (const unsigned char*)d_in[2];
    const float* W1  = (const float*)d_in[3];
    const float* b1  = (const float*)d_in[4];
    const float* g1  = (const float*)d_in[5];
    const float* be1 = (const float*)d_in[6];
    const float* m1  = (const float*)d_in[7];
    const float* v1  = (const float*)d_in[8];
    const float* W2  = (const float*)d_in[9];
    const float* b2  = (const float*)d_in[10];
    const float* g2  = (const float*)d_in[11];
    const float* be2 = (const float*)d_in[12];
    const float* m2  = (const float*)d_in[13];
    const float* v2  = (const float*)d_in[14];
    const float* W3  = (const float*)d_in[15];
    const float* b3  = (const float*)d_in[16];
    const float* g3  = (const float*)d_in[17];
    const float* be3 = (const float*)d_in[18];
    const float* m3  = (const float*)d_in[19];
    const float* v3  = (const float*)d_in[20];
    const float* Wih = (const float*)d_in[21];
    const float* Whh = (const float*)d_in[22];
    const float* bih = (const float*)d_in[23];
    const float* bhh = (const float*)d_in[24];
    const float* Wf  = (const float*)d_in[25];
    const float* bf  = (const float*)d_in[26];

    char* w = (char*)d_ws;
    unsigned int* WhhP = (unsigned int*)(w + 0);        // 393216 B (in 786432 slot)
    float* WxT = (float*)(w + 786432);                  // 393216 B
    float* W2T = (float*)(w + 1179648);                 // 1638400 B
    float* W3T = (float*)(w + 2818048);                 // 1638400 B
    int*   flag = (int*)(w + 4456448);                  // 512 B slot
    float* X1  = (float*)(w + 4456960);                 // 128 MB; reused as Gx after conv2
    float* Gx  = X1;
    float* X2  = (float*)(w + 4456960 + 134217728);     // 32 MB
    float* F   = (float*)(w + 4456960 + 134217728 + 33554432); // 16 MB
    float* out = (float*)d_out;

    k_prep<<<1600, 256, 0, stream>>>(Wih, Whh, W2, W3, fmask, WhhP, WxT, W2T, W3T, flag);
    k_conv1<<<8192, 256, 0, stream>>>(features, W1, b1, g1, be1, m1, v1, X1);
    k_conv2<<<1024, 256, 0, stream>>>(X1, W2T, b2, g2, be2, m2, v2, X2);
    k_conv3<<<1024, 256, 0, stream>>>(X2, W3T, b3, g3, be3, m3, v3, F);
    k_gemm<<<1536, 256, 0, stream>>>(F, WxT, bih, Gx);
    k_gru2<<<32, 512, 0, stream>>>((const u32x4*)WhhP, Gx, Wih, bhh, Wf, bf,
                                   targets, fmask, flag, out);
}

// Round 7
// 5770.397 us; speedup vs baseline: 1.3441x; 1.1012x over previous
//
#include <hip/hip_runtime.h>
#include <math.h>

#define EPSF 1e-5f

typedef __attribute__((ext_vector_type(2))) float f2;
typedef __attribute__((ext_vector_type(4))) float f4;
typedef __attribute__((ext_vector_type(8))) _Float16 f16x8;

// packed fp32 FMA with x broadcast via op_sel (lo or hi half of the x pair)
#define PK_FMA_LO(ACC, W, X) \
    asm("v_pk_fma_f32 %0, %1, %2, %0 op_sel:[0,0,0] op_sel_hi:[1,0,1]" \
        : "+v"(ACC) : "v"(W), "v"(X))
#define PK_FMA_HI(ACC, W, X) \
    asm("v_pk_fma_f32 %0, %1, %2, %0 op_sel:[0,1,0] op_sel_hi:[1,1,1]" \
        : "+v"(ACC) : "v"(W), "v"(X))

// DPP helper: v += value from lane (i - N) within the 16-lane DPP row (0 if OOB)
template<int CTRL>
__device__ __forceinline__ float dpp_add(float v) {
    int s = __builtin_amdgcn_update_dpp(0, __float_as_int(v), CTRL, 0xf, 0xf, true);
    return v + __int_as_float(s);
}

// hq swizzle: +4 floats of pad per 16 (stride 20)
#define HQ(d) ((d) + (((d) >> 4) << 2))

// ---------------- prep: weight transposes + bool-dtype detect ----------------
// WhhP: MFMA A-fragment layout for k_gru2 (256 threads, 4 waves).
//   tile T = RT*8 + kt (RT 0..47 row-tiles of 16, kt 0..7 K-tiles of 32).
//   lane holds A[row = lane&15][k = kt*32 + (lane>>4)*8 + e], e=0..7, packed
//   2 fp16/dword, dword j = elements 2j,2j+1. dword idx = (T*64+lane)*4 + j.
__global__ __launch_bounds__(256) void k_prep(
    const float* __restrict__ Wih, const float* __restrict__ Whh,
    const float* __restrict__ W2, const float* __restrict__ W3,
    const unsigned char* __restrict__ fmask,
    unsigned int* __restrict__ WhhP, float* __restrict__ WxT,
    float* __restrict__ W2T, float* __restrict__ W3T, int* __restrict__ flag)
{
    int idx = blockIdx.x * 256 + threadIdx.x;
    if (idx < 98304) {                  // Whh -> MFMA A-frag layout
        int T = idx >> 8;
        int lane = (idx >> 2) & 63;
        int j = idx & 3;
        int RT = T >> 3, kt = T & 7;
        int row = RT * 16 + (lane & 15);
        int col = kt * 32 + (lane >> 4) * 8 + j * 2;
        union { _Float16 h[2]; unsigned int u; } pk;
        pk.h[0] = (_Float16)Whh[row * 256 + col];
        pk.h[1] = (_Float16)Whh[row * 256 + col + 1];
        WhhP[idx] = pk.u;
    }
    if (idx < 105984) {                 // Wih[768][138] x-part -> WxT[128][768]
        int j = idx / 138, k = idx % 138;
        if (k < 128) WxT[k * 768 + j] = Wih[idx];
    }
    if (idx < 409600) {                 // W[co][ci][5][5] -> WT[tap][ci][co]
        int co = idx / 3200, r = idx % 3200;
        int ci = r / 25, tap = r % 25;
        int dst = (tap * 128 + ci) * 128 + co;
        W2T[dst] = W2[idx];
        W3T[dst] = W3[idx];
    }
    if (idx == 0) {                     // bool stored as int32?
        int nz = 0;
        for (int i = 0; i < 4096; i++) if ((i & 3) != 0) nz |= fmask[i];
        *flag = nz ? 0 : 1;
    }
}

// ---------------- conv1: [32,1,1024,40] -> X1[b][t][m1(8)][co(128)] ----------------
__global__ __launch_bounds__(256) void k_conv1(
    const float* __restrict__ X, const float* __restrict__ W1,
    const float* __restrict__ bb, const float* __restrict__ gg,
    const float* __restrict__ be, const float* __restrict__ mm_,
    const float* __restrict__ vv, float* __restrict__ X1)
{
    __shared__ __align__(16) float xs[8][44];
    __shared__ __align__(16) float ws[25][128];
    __shared__ float sc[128], sh[128];
    int bid = blockIdx.x;
    int b = bid >> 8, t0 = (bid & 255) << 2;
    int tid = threadIdx.x;
    for (int e = tid; e < 8 * 44; e += 256) {
        int tt = e / 44, mm = e % 44;
        int gt = t0 + tt - 2, gm = mm - 2;
        float val = 0.f;
        if (gt >= 0 && gt < 1024 && gm >= 0 && gm < 40)
            val = X[(b * 1024 + gt) * 40 + gm];
        xs[tt][mm] = val;
    }
    for (int e = tid; e < 3200; e += 256) {
        int tap = e >> 7, co = e & 127;
        ws[tap][co] = W1[co * 25 + tap];
    }
    if (tid < 128) {
        float s = gg[tid] / sqrtf(vv[tid] + EPSF);
        sc[tid] = s;
        sh[tid] = (bb[tid] - mm_[tid]) * s + be[tid];
    }
    __syncthreads();
    int cog = tid >> 5;          // 8 groups x 16 co
    int m1i = (tid >> 2) & 7;    // pooled mel
    int tp  = tid & 3;           // t'
    int co0 = cog * 16;
    float val[5][16];
#pragma unroll
    for (int p = 0; p < 5; p++)
#pragma unroll
        for (int i = 0; i < 16; i++) val[p][i] = 0.f;
#pragma unroll
    for (int dt = 0; dt < 5; dt++) {
#pragma unroll
        for (int dm = 0; dm < 5; dm++) {
            float w[16];
#pragma unroll
            for (int i = 0; i < 16; i += 4)
                *(float4*)&w[i] = *(const float4*)&ws[dt * 5 + dm][co0 + i];
#pragma unroll
            for (int p = 0; p < 5; p++) {
                float x = xs[tp + dt][m1i * 5 + p + dm];
#pragma unroll
                for (int i = 0; i < 16; i++) val[p][i] = fmaf(x, w[i], val[p][i]);
            }
        }
    }
    float outv[16];
#pragma unroll
    for (int i = 0; i < 16; i++) {
        float s = sc[co0 + i], h = sh[co0 + i];
        float mx = 0.f;
#pragma unroll
        for (int p = 0; p < 5; p++) {
            float y = fmaf(val[p][i], s, h);
            y = fmaxf(y, 0.f);
            mx = fmaxf(mx, y);
        }
        outv[i] = mx;
    }
    float* dst = &X1[(((long)(b * 1024 + t0 + tp)) * 8 + m1i) * 128 + co0];
#pragma unroll
    for (int i = 0; i < 16; i += 4) *(float4*)&dst[i] = *(float4*)&outv[i];
}

// -------- conv2 v5: ci-chunk 8, LDS 36KB -> 4 blocks/CU (R4-validated) --------
__global__ __launch_bounds__(256) void k_conv2(
    const float* __restrict__ X1, const float* __restrict__ W2T,
    const float* __restrict__ bb, const float* __restrict__ gg,
    const float* __restrict__ be, const float* __restrict__ mm_,
    const float* __restrict__ vv, float* __restrict__ X2)
{
    __shared__ __align__(16) float xs[36 * 100];    // [tt][ci*12 + m], ci<8
    __shared__ __align__(16) float ws[5 * 8 * 128]; // [dm][ci][co]
    __shared__ float sc[128], sh[128];
    int bid = blockIdx.x;
    int t0 = (bid & 31) << 5, b = bid >> 5;
    int tid = threadIdx.x;
    int tp = tid & 15, cog = tid >> 4;
    if (tid < 128) {
        float s = gg[tid] / sqrtf(vv[tid] + EPSF);
        sc[tid] = s;
        sh[tid] = (bb[tid] - mm_[tid]) * s + be[tid];
    }
    f2 accp[2][4][8];                    // [t-half][co pair][m]
#pragma unroll
    for (int th = 0; th < 2; th++)
#pragma unroll
        for (int p = 0; p < 4; p++)
#pragma unroll
            for (int m = 0; m < 8; m++) accp[th][p][m] = (f2){0.f, 0.f};

    for (int cc = 0; cc < 16; cc++) {
        __syncthreads();
        for (int e = tid; e < 864; e += 256) {
            int ci = e & 7, r = e >> 3;           // r 0..107
            int tt = r / 3, mg = r - tt * 3;
            int gt = t0 + tt - 2;
            float4 v = {0.f, 0.f, 0.f, 0.f};
            if (gt >= 0 && gt < 1024) {
                const float* src = &X1[(((long)(b * 1024 + gt)) * 8) * 128 + cc * 8 + ci];
                float* pv = (float*)&v;
#pragma unroll
                for (int k2 = 0; k2 < 4; k2++) {
                    int gm = mg * 4 + k2 - 2;
                    if (gm >= 0 && gm < 8) pv[k2] = src[gm * 128];
                }
            }
            *(float4*)&xs[tt * 100 + ci * 12 + mg * 4] = v;
        }
        for (int dt = 0; dt < 5; dt++) {
            __syncthreads();
            for (int e = tid; e < 5120; e += 256) {
                int co = e & 127, ci = (e >> 7) & 7, dm = e >> 10;
                ws[dm * 1024 + ci * 128 + co] =
                    W2T[((dt * 5 + dm) * 128 + cc * 8 + ci) * 128 + co];
            }
            __syncthreads();
            for (int ci = 0; ci < 8; ci++) {
                f2 x2[2][6];
#pragma unroll
                for (int th = 0; th < 2; th++) {
                    const float* xp = &xs[(tp + th * 16 + dt) * 100 + ci * 12];
                    f4 a = *(const f4*)&xp[0];
                    f4 bv = *(const f4*)&xp[4];
                    f4 cv = *(const f4*)&xp[8];
                    x2[th][0] = (f2){a.x, a.y};   x2[th][1] = (f2){a.z, a.w};
                    x2[th][2] = (f2){bv.x, bv.y}; x2[th][3] = (f2){bv.z, bv.w};
                    x2[th][4] = (f2){cv.x, cv.y}; x2[th][5] = (f2){cv.z, cv.w};
                }
                const float* wb = &ws[ci * 128];
#pragma unroll
                for (int dm = 0; dm < 5; dm++) {
                    const float* wr = wb + dm * 1024;
                    f4 wa = *(const f4*)&wr[cog * 4];
                    f4 wbv = *(const f4*)&wr[64 + cog * 4];
                    f2 wp[4];
                    wp[0] = (f2){wa.x, wa.y};   wp[1] = (f2){wa.z, wa.w};
                    wp[2] = (f2){wbv.x, wbv.y}; wp[3] = (f2){wbv.z, wbv.w};
#pragma unroll
                    for (int th = 0; th < 2; th++)
#pragma unroll
                        for (int m = 0; m < 8; m++) {
                            const int j = m + dm;
                            f2 xpair = x2[th][j >> 1];
                            if (j & 1) {
                                PK_FMA_HI(accp[th][0][m], wp[0], xpair);
                                PK_FMA_HI(accp[th][1][m], wp[1], xpair);
                                PK_FMA_HI(accp[th][2][m], wp[2], xpair);
                                PK_FMA_HI(accp[th][3][m], wp[3], xpair);
                            } else {
                                PK_FMA_LO(accp[th][0][m], wp[0], xpair);
                                PK_FMA_LO(accp[th][1][m], wp[1], xpair);
                                PK_FMA_LO(accp[th][2][m], wp[2], xpair);
                                PK_FMA_LO(accp[th][3][m], wp[3], xpair);
                            }
                        }
                }
            }
        }
    }
#pragma unroll
    for (int th = 0; th < 2; th++) {
        int t = t0 + th * 16 + tp;
#pragma unroll
        for (int g = 0; g < 2; g++) {
            int cobase = g * 64 + cog * 4;
#pragma unroll
            for (int m2 = 0; m2 < 2; m2++) {
                float4 ov;
                float* po = (float*)&ov;
#pragma unroll
                for (int c = 0; c < 4; c++) {
                    float s = sc[cobase + c], h = sh[cobase + c];
                    float mx = 0.f;
#pragma unroll
                    for (int q = 0; q < 4; q++) {
                        f2 av = accp[th][g * 2 + (c >> 1)][m2 * 4 + q];
                        float a = (c & 1) ? av.y : av.x;
                        float y = fmaf(a, s, h);
                        y = fmaxf(y, 0.f);
                        mx = fmaxf(mx, y);
                    }
                    po[c] = mx;
                }
                *(float4*)&X2[(((long)(b * 1024 + t)) * 2 + m2) * 128 + cobase] = ov;
            }
        }
    }
}

// ------- conv3 v2: t-tile 64, ws staging amortized 4x (R4-validated) -------
__global__ __launch_bounds__(256) void k_conv3(
    const float* __restrict__ X2, const float* __restrict__ W3T,
    const float* __restrict__ bb, const float* __restrict__ gg,
    const float* __restrict__ be, const float* __restrict__ mm_,
    const float* __restrict__ vv, float* __restrict__ F)
{
    __shared__ __align__(16) float xs[68 * 66];     // [t''][ci*2+m], stride 66
    __shared__ __align__(16) float ws[3][32][64];   // [dm-1][ci][co]
    __shared__ float sc[64], sh[64];
    int bid = blockIdx.x;
    int coh = bid & 1, t0 = ((bid >> 1) & 15) << 6, b = bid >> 5;
    int co_base = coh * 64;
    int tid = threadIdx.x;
    int tp = tid & 15, cog = tid >> 4;
    if (tid < 64) {
        int co = co_base + tid;
        float s = gg[co] / sqrtf(vv[co] + EPSF);
        sc[tid] = s;
        sh[tid] = (bb[co] - mm_[co]) * s + be[co];
    }
    float acc[4][4][2];                              // [t-chunk][c][pos]
#pragma unroll
    for (int tc = 0; tc < 4; tc++)
#pragma unroll
        for (int c = 0; c < 4; c++) { acc[tc][c][0] = 0.f; acc[tc][c][1] = 0.f; }

    for (int cc = 0; cc < 4; cc++) {
        __syncthreads();
        for (int e = tid; e < 68 * 64; e += 256) {
            int tt = e >> 6, r = e & 63;
            int ci = r >> 1, m = r & 1;
            int gt = t0 + tt - 2;
            float v = 0.f;
            if (gt >= 0 && gt < 1024)
                v = X2[(((long)(b * 1024 + gt)) * 2 + m) * 128 + cc * 32 + ci];
            xs[tt * 66 + ci * 2 + m] = v;
        }
        for (int dt = 0; dt < 5; dt++) {
            __syncthreads();
            for (int e = tid; e < 3 * 32 * 64; e += 256) {
                int co = e & 63, ci = (e >> 6) & 31, dmi = e >> 11;
                ws[dmi][ci][co] = W3T[((dt * 5 + dmi + 1) * 128 + cc * 32 + ci) * 128 + co_base + co];
            }
            __syncthreads();
            for (int ci = 0; ci < 32; ci++) {
                float w1[4], w2[4], w3[4];
                *(float4*)w1 = *(const float4*)&ws[0][ci][cog * 4];
                *(float4*)w2 = *(const float4*)&ws[1][ci][cog * 4];
                *(float4*)w3 = *(const float4*)&ws[2][ci][cog * 4];
#pragma unroll
                for (int tc = 0; tc < 4; tc++) {
                    float2 x = *(const float2*)&xs[(tc * 16 + tp + dt) * 66 + ci * 2];
#pragma unroll
                    for (int c = 0; c < 4; c++) acc[tc][c][0] = fmaf(w2[c], x.x, acc[tc][c][0]);
#pragma unroll
                    for (int c = 0; c < 4; c++) acc[tc][c][0] = fmaf(w3[c], x.y, acc[tc][c][0]);
#pragma unroll
                    for (int c = 0; c < 4; c++) acc[tc][c][1] = fmaf(w1[c], x.x, acc[tc][c][1]);
#pragma unroll
                    for (int c = 0; c < 4; c++) acc[tc][c][1] = fmaf(w2[c], x.y, acc[tc][c][1]);
                }
            }
        }
    }
#pragma unroll
    for (int tc = 0; tc < 4; tc++) {
        float4 ov;
        float* po = (float*)&ov;
#pragma unroll
        for (int c = 0; c < 4; c++) {
            float s = sc[cog * 4 + c], h = sh[cog * 4 + c];
            float y0 = fmaxf(fmaf(acc[tc][c][0], s, h), 0.f);
            float y1 = fmaxf(fmaf(acc[tc][c][1], s, h), 0.f);
            po[c] = fmaxf(y0, y1);
        }
        *(float4*)&F[((long)(t0 + tc * 16 + tp) * 32 + b) * 128 + co_base + cog * 4] = ov;
    }
}

// ---------------- Gx = F @ Wihx.T + bih : [32768,128]x[128,768] ----------------
__global__ __launch_bounds__(256) void k_gemm(
    const float* __restrict__ F, const float* __restrict__ WxT,
    const float* __restrict__ bih, float* __restrict__ Gx)
{
    __shared__ __align__(16) float Fs[64][33];
    __shared__ __align__(16) float Ws[32][256];
    int bid = blockIdx.x;
    int jt = bid % 3, tb0 = (bid / 3) * 64;
    int tid = threadIdx.x;
    int tx = tid & 31, ty = tid >> 5;
    float acc[8][8];
#pragma unroll
    for (int i = 0; i < 8; i++)
#pragma unroll
        for (int j = 0; j < 8; j++) acc[i][j] = 0.f;
    for (int cc = 0; cc < 4; cc++) {
        __syncthreads();
        for (int e = tid; e < 64 * 32; e += 256) {
            int ci = e & 31, i = e >> 5;
            Fs[i][ci] = F[(long)(tb0 + i) * 128 + cc * 32 + ci];
        }
        for (int e = tid; e < 32 * 256; e += 256) {
            int jj = e & 255, ci = e >> 8;
            Ws[ci][jj] = WxT[(cc * 32 + ci) * 768 + jt * 256 + jj];
        }
        __syncthreads();
        for (int ci = 0; ci < 32; ci++) {
            float a[8], w[8];
#pragma unroll
            for (int i = 0; i < 8; i++) a[i] = Fs[ty * 8 + i][ci];
            *(float4*)&w[0] = *(const float4*)&Ws[ci][tx * 8];
            *(float4*)&w[4] = *(const float4*)&Ws[ci][tx * 8 + 4];
#pragma unroll
            for (int i = 0; i < 8; i++)
#pragma unroll
                for (int j = 0; j < 8; j++) acc[i][j] = fmaf(a[i], w[j], acc[i][j]);
        }
    }
    float bj[8];
#pragma unroll
    for (int j = 0; j < 8; j++) bj[j] = bih[jt * 256 + tx * 8 + j];
#pragma unroll
    for (int i = 0; i < 8; i++) {
        float o[8];
#pragma unroll
        for (int j = 0; j < 8; j++) o[j] = acc[i][j] + bj[j];
        float* dst = &Gx[(long)(tb0 + ty * 8 + i) * 768 + jt * 256 + tx * 8];
        *(float4*)&dst[0] = *(float4*)&o[0];
        *(float4*)&dst[4] = *(float4*)&o[4];
    }
}

// ====== GRU v10: builtin-MFMA matvec, Whh pinned in VGPRs (no AGPR) ======
// R5+R6 post-mortem: NaN with BOTH asm and builtin MFMA; the only shared
// exotic element was the A-operand in the AGPR class (R5 "a" constraint,
// R6 "+a" pin on 96 4-reg tuples) -- garbage-register read is the only
// NaN mechanism consistent with bounded GRU math. v10 removes AGPR use
// entirely: "+v" opaque pin (proven constraint class) keeps the 384
// weight VGPRs live (no remat, the R1-R3 failure) under the 512-reg
// budget of waves_per_eu(1,1) (m08: no spill through 450 regs).
// Simplified: h goes to MFMA as plain fp16 (no hi/lo residual columns,
// no dpp on MFMA results). B[k][col] = h[k] for every col -> D[:,col]
// identical; col-0 lanes write gsum rows via the m89-VERIFIED C/D map
// (col=lane&15, row=(lane>>4)*4+reg). The (lane,elem)->k map cancels
// between A and B whatever it is (both fragments use the same map).
__global__ __attribute__((amdgpu_waves_per_eu(1, 1))) __launch_bounds__(256) void k_gru2(
    const f16x8* __restrict__ Wp8, const float* __restrict__ Gx,
    const float* __restrict__ Wih, const float* __restrict__ bhh_g,
    const float* __restrict__ Wf, const float* __restrict__ bf_g,
    const float* __restrict__ targets, const unsigned char* __restrict__ fmask,
    const int* __restrict__ flag, float* __restrict__ out)
{
    __shared__ __align__(16) float hq[320];      // swizzled fp32 h (proj)
    __shared__ __align__(16) _Float16 hqh[256];  // fp16(h) (MFMA B)
    __shared__ __align__(16) float gsum[768];
    __shared__ float tfl[16];
    __shared__ float bhL[768];
    __shared__ __align__(16) float wtfL[7680];   // [cp(30)][256]
    __shared__ __align__(16) float WfL[3200];    // [oc(10)][seg*20], padded
    const int b = blockIdx.x, tid = threadIdx.x;
    const int wv = tid >> 6, l = tid & 63;
    const int kg = l >> 4;                       // k-group within wave
    const int cl = l & 15;                       // MFMA column of this lane
    const bool isProj = (tid < 160);
    const int oc = tid >> 4, seg = tid & 15;
    const bool isWr = isProj && (seg == 15);

    // ---- weights: 96 A-fragments/lane, coalesced 16B loads ----
    f16x8 wq[96];
    {
        const f16x8* wp = Wp8 + (long)(wv * 96) * 64 + l;
#pragma unroll
        for (int q = 0; q < 96; q++) wq[q] = wp[q * 64];
    }
    // opaque VGPR pin: allocator can neither remat the load nor sink it
#pragma unroll
    for (int q = 0; q < 96; q++) asm volatile("" : "+v"(wq[q]));

    // ---- one-time LDS fills ----
    for (int e = tid; e < 7680; e += 256) {
        int cp = e >> 8, jj = e & 255;
        int gg = cp / 10, c = cp - gg * 10;
        wtfL[e] = Wih[(gg * 256 + jj) * 138 + 128 + c];
    }
    for (int e = tid; e < 3200; e += 256) {
        int oo = e / 320, rem = e - oo * 320;
        int sg = rem / 20, ii = rem - sg * 20;
        WfL[e] = (ii < 16) ? Wf[oo * 256 + sg * 16 + ii] : 0.f;
    }
    for (int e = tid; e < 768; e += 256) { bhL[e] = bhh_g[e]; gsum[e] = 0.f; }
    for (int e = tid; e < 320; e += 256) hq[e] = 0.f;
    hqh[tid] = (_Float16)0.f;
    if (tid < 16) tfl[tid] = 0.f;
    float bfc = isProj ? bf_g[oc] : 0.f;
    const int int32mode = flag[0];
    float hold = 0.f;                            // this thread's h[tid]
    __syncthreads();

    for (int t = 0; t < 1024; t++) {
        // per-step global loads issued early, consumed after B1
        const float* gx = &Gx[((long)t * 32 + b) * 768];
        float gxr = gx[tid], gxz = gx[tid + 256], gxn = gx[tid + 512];
        float tgt = 0.f; int fmv = 0;
        if (isWr) {
            tgt = targets[((long)b * 1024 + t) * 10 + oc];
            fmv = int32mode ? ((const int*)fmask)[t * 32 + b] : (int)fmask[t * 32 + b];
        }

        // ---- MFMA matvec: 12 row-tiles x 8 K-tiles ----
        f4 acc[12];
#pragma unroll
        for (int rt = 0; rt < 12; rt++) acc[rt] = (f4){0.f, 0.f, 0.f, 0.f};
#pragma unroll
        for (int kt = 0; kt < 8; kt++) {
            f16x8 bv = *(const f16x8*)&hqh[kt * 32 + kg * 8];
#pragma unroll
            for (int rt = 0; rt < 12; rt++)
                acc[rt] = __builtin_amdgcn_mfma_f32_16x16x32_f16(
                    wq[rt * 8 + kt], bv, acc[rt], 0, 0, 0);
        }
        // col-0 lanes hold the matvec (all cols identical); write 4 rows each
        if (cl == 0) {
#pragma unroll
            for (int rt = 0; rt < 12; rt++)
                *(f4*)&gsum[(wv * 12 + rt) * 16 + kg * 4] = acc[rt];
        }
        __syncthreads();   // B1: gsum ready; hqh reads of step t complete

        {   // gate phase: all 256 threads, one hidden unit each
            float gr = gxr, gz = gxz, gn = gxn;
#pragma unroll
            for (int c = 0; c < 10; c++) {
                float tv = tfl[c];
                gr = fmaf(tv, wtfL[c * 256 + tid], gr);
                gz = fmaf(tv, wtfL[(10 + c) * 256 + tid], gz);
                gn = fmaf(tv, wtfL[(20 + c) * 256 + tid], gn);
            }
            float ar = gsum[tid] + bhL[tid];
            float az = gsum[tid + 256] + bhL[tid + 256];
            float an = gsum[tid + 512] + bhL[tid + 512];
            float r = 1.0f / (1.0f + expf(-(gr + ar)));
            float z = 1.0f / (1.0f + expf(-(gz + az)));
            float n = tanhf(fmaf(r, an, gn));
            float hnew = (1.0f - z) * n + z * hold;
            hold = hnew;
            hq[HQ(tid)] = hnew;
            hqh[tid] = (_Float16)hnew;
        }
        __syncthreads();   // B2: h ready

        if (isProj) {
            float s = 0.f;
#pragma unroll
            for (int qq = 0; qq < 4; qq++) {
                f4 h4 = *(const f4*)&hq[seg * 20 + qq * 4];
                f4 wvv = *(const f4*)&WfL[oc * 320 + seg * 20 + qq * 4];
                s = fmaf(wvv.x, h4.x, s);
                s = fmaf(wvv.y, h4.y, s);
                s = fmaf(wvv.z, h4.z, s);
                s = fmaf(wvv.w, h4.w, s);
            }
            s = dpp_add<0x111>(s);
            s = dpp_add<0x112>(s);
            s = dpp_add<0x114>(s);
            s = dpp_add<0x118>(s);
            if (isWr) {
                float o = s + bfc;
                out[((long)b * 1024 + t) * 10 + oc] = o;
                float pred = (o > 0.f) ? 1.f : 0.f;
                tfl[oc] = fmv ? tgt : pred;
            }
        }
        // ordering: gates(t) read gsum before B2(t); matvec(t+1) writes gsum
        // after B2(t). matvec(t+1) reads hqh after B2(t); gates(t) wrote it
        // before B2(t). proj(t) reads hq/tfl between B2(t) and B1(t+1);
        // gates touch them only after B1(t+1). No races.
    }
}

extern "C" void kernel_launch(void* const* d_in, const int* in_sizes, int n_in,
                              void* d_out, int out_size, void* d_ws, size_t ws_size,
                              hipStream_t stream) {
    (void)in_sizes; (void)n_in; (void)out_size; (void)ws_size;
    const float* features = (const float*)d_in[0];
    const float* targets  = (const float*)d_in[1];
    const unsigned char* fmask = (const unsigned char*)d_in[2];
    const float* W1  = (const float*)d_in[3];
    const float* b1  = (const float*)d_in[4];
    const float* g1  = (const float*)d_in[5];
    const float* be1 = (const float*)d_in[6];
    const float* m1  = (const float*)d_in[7];
    const float* v1  = (const float*)d_in[8];
    const float* W2  = (const float*)d_in[9];
    const float* b2  = (const float*)d_in[10];
    const float* g2  = (const float*)d_in[11];
    const float* be2 = (const float*)d_in[12];
    const float* m2  = (const float*)d_in[13];
    const float* v2  = (const float*)d_in[14];
    const float* W3  = (const float*)d_in[15];
    const float* b3  = (const float*)d_in[16];
    const float* g3  = (const float*)d_in[17];
    const float* be3 = (const float*)d_in[18];
    const float* m3  = (const float*)d_in[19];
    const float* v3  = (const float*)d_in[20];
    const float* Wih = (const float*)d_in[21];
    const float* Whh = (const float*)d_in[22];
    const float* bih = (const float*)d_in[23];
    const float* bhh = (const float*)d_in[24];
    const float* Wf  = (const float*)d_in[25];
    const float* bf  = (const float*)d_in[26];

    char* w = (char*)d_ws;
    unsigned int* WhhP = (unsigned int*)(w + 0);        // 393216 B (in 786432 slot)
    float* WxT = (float*)(w + 786432);                  // 393216 B
    float* W2T = (float*)(w + 1179648);                 // 1638400 B
    float* W3T = (float*)(w + 2818048);                 // 1638400 B
    int*   flag = (int*)(w + 4456448);                  // 512 B slot
    float* X1  = (float*)(w + 4456960);                 // 128 MB; reused as Gx after conv2
    float* Gx  = X1;
    float* X2  = (float*)(w + 4456960 + 134217728);     // 32 MB
    float* F   = (float*)(w + 4456960 + 134217728 + 33554432); // 16 MB
    float* out = (float*)d_out;

    k_prep<<<1600, 256, 0, stream>>>(Wih, Whh, W2, W3, fmask, WhhP, WxT, W2T, W3T, flag);
    k_conv1<<<8192, 256, 0, stream>>>(features, W1, b1, g1, be1, m1, v1, X1);
    k_conv2<<<1024, 256, 0, stream>>>(X1, W2T, b2, g2, be2, m2, v2, X2);
    k_conv3<<<1024, 256, 0, stream>>>(X2, W3T, b3, g3, be3, m3, v3, F);
    k_gemm<<<1536, 256, 0, stream>>>(F, WxT, bih, Gx);
    k_gru2<<<32, 256, 0, stream>>>((const f16x8*)WhhP, Gx, Wih, bhh, Wf, bf,
                                   targets, fmask, flag, out);
}

// Round 8
// 5678.802 us; speedup vs baseline: 1.3657x; 1.0161x over previous
//
#include <hip/hip_runtime.h>
#include <math.h>

#define EPSF 1e-5f

typedef __attribute__((ext_vector_type(2))) float f2;
typedef __attribute__((ext_vector_type(4))) float f4;
typedef __attribute__((ext_vector_type(8))) _Float16 f16x8;

// packed fp32 FMA with x broadcast via op_sel (lo or hi half of the x pair)
#define PK_FMA_LO(ACC, W, X) \
    asm("v_pk_fma_f32 %0, %1, %2, %0 op_sel:[0,0,0] op_sel_hi:[1,0,1]" \
        : "+v"(ACC) : "v"(W), "v"(X))
#define PK_FMA_HI(ACC, W, X) \
    asm("v_pk_fma_f32 %0, %1, %2, %0 op_sel:[0,1,0] op_sel_hi:[1,1,1]" \
        : "+v"(ACC) : "v"(W), "v"(X))

// DPP helper: v += value from lane (i - N) within the 16-lane DPP row (0 if OOB)
template<int CTRL>
__device__ __forceinline__ float dpp_add(float v) {
    int s = __builtin_amdgcn_update_dpp(0, __float_as_int(v), CTRL, 0xf, 0xf, true);
    return v + __int_as_float(s);
}

// hq swizzle: +4 floats of pad per 16 (stride 20)
#define HQ(d) ((d) + (((d) >> 4) << 2))

// ---------------- prep: weight transposes + bool-dtype detect ----------------
// WhhP: MFMA A-fragment layout (tile-major, wave-agnostic).
//   tile T = RT*8 + kt (RT 0..47 row-tiles of 16, kt 0..7 K-tiles of 32).
//   lane holds A[row = lane&15][k = kt*32 + (lane>>4)*8 + e], e=0..7, packed
//   2 fp16/dword, dword j = elements 2j,2j+1. dword idx = (T*64+lane)*4 + j.
__global__ __launch_bounds__(256) void k_prep(
    const float* __restrict__ Wih, const float* __restrict__ Whh,
    const float* __restrict__ W2, const float* __restrict__ W3,
    const unsigned char* __restrict__ fmask,
    unsigned int* __restrict__ WhhP, float* __restrict__ WxT,
    float* __restrict__ W2T, float* __restrict__ W3T, int* __restrict__ flag)
{
    int idx = blockIdx.x * 256 + threadIdx.x;
    if (idx < 98304) {                  // Whh -> MFMA A-frag layout
        int T = idx >> 8;
        int lane = (idx >> 2) & 63;
        int j = idx & 3;
        int RT = T >> 3, kt = T & 7;
        int row = RT * 16 + (lane & 15);
        int col = kt * 32 + (lane >> 4) * 8 + j * 2;
        union { _Float16 h[2]; unsigned int u; } pk;
        pk.h[0] = (_Float16)Whh[row * 256 + col];
        pk.h[1] = (_Float16)Whh[row * 256 + col + 1];
        WhhP[idx] = pk.u;
    }
    if (idx < 105984) {                 // Wih[768][138] x-part -> WxT[128][768]
        int j = idx / 138, k = idx % 138;
        if (k < 128) WxT[k * 768 + j] = Wih[idx];
    }
    if (idx < 409600) {                 // W[co][ci][5][5] -> WT[tap][ci][co]
        int co = idx / 3200, r = idx % 3200;
        int ci = r / 25, tap = r % 25;
        int dst = (tap * 128 + ci) * 128 + co;
        W2T[dst] = W2[idx];
        W3T[dst] = W3[idx];
    }
    if (idx == 0) {                     // bool stored as int32?
        int nz = 0;
        for (int i = 0; i < 4096; i++) if ((i & 3) != 0) nz |= fmask[i];
        *flag = nz ? 0 : 1;
    }
}

// ---------------- conv1: [32,1,1024,40] -> X1[b][t][m1(8)][co(128)] ----------------
__global__ __launch_bounds__(256) void k_conv1(
    const float* __restrict__ X, const float* __restrict__ W1,
    const float* __restrict__ bb, const float* __restrict__ gg,
    const float* __restrict__ be, const float* __restrict__ mm_,
    const float* __restrict__ vv, float* __restrict__ X1)
{
    __shared__ __align__(16) float xs[8][44];
    __shared__ __align__(16) float ws[25][128];
    __shared__ float sc[128], sh[128];
    int bid = blockIdx.x;
    int b = bid >> 8, t0 = (bid & 255) << 2;
    int tid = threadIdx.x;
    for (int e = tid; e < 8 * 44; e += 256) {
        int tt = e / 44, mm = e % 44;
        int gt = t0 + tt - 2, gm = mm - 2;
        float val = 0.f;
        if (gt >= 0 && gt < 1024 && gm >= 0 && gm < 40)
            val = X[(b * 1024 + gt) * 40 + gm];
        xs[tt][mm] = val;
    }
    for (int e = tid; e < 3200; e += 256) {
        int tap = e >> 7, co = e & 127;
        ws[tap][co] = W1[co * 25 + tap];
    }
    if (tid < 128) {
        float s = gg[tid] / sqrtf(vv[tid] + EPSF);
        sc[tid] = s;
        sh[tid] = (bb[tid] - mm_[tid]) * s + be[tid];
    }
    __syncthreads();
    int cog = tid >> 5;          // 8 groups x 16 co
    int m1i = (tid >> 2) & 7;    // pooled mel
    int tp  = tid & 3;           // t'
    int co0 = cog * 16;
    float val[5][16];
#pragma unroll
    for (int p = 0; p < 5; p++)
#pragma unroll
        for (int i = 0; i < 16; i++) val[p][i] = 0.f;
#pragma unroll
    for (int dt = 0; dt < 5; dt++) {
#pragma unroll
        for (int dm = 0; dm < 5; dm++) {
            float w[16];
#pragma unroll
            for (int i = 0; i < 16; i += 4)
                *(float4*)&w[i] = *(const float4*)&ws[dt * 5 + dm][co0 + i];
#pragma unroll
            for (int p = 0; p < 5; p++) {
                float x = xs[tp + dt][m1i * 5 + p + dm];
#pragma unroll
                for (int i = 0; i < 16; i++) val[p][i] = fmaf(x, w[i], val[p][i]);
            }
        }
    }
    float outv[16];
#pragma unroll
    for (int i = 0; i < 16; i++) {
        float s = sc[co0 + i], h = sh[co0 + i];
        float mx = 0.f;
#pragma unroll
        for (int p = 0; p < 5; p++) {
            float y = fmaf(val[p][i], s, h);
            y = fmaxf(y, 0.f);
            mx = fmaxf(mx, y);
        }
        outv[i] = mx;
    }
    float* dst = &X1[(((long)(b * 1024 + t0 + tp)) * 8 + m1i) * 128 + co0];
#pragma unroll
    for (int i = 0; i < 16; i += 4) *(float4*)&dst[i] = *(float4*)&outv[i];
}

// -------- conv2 v5: ci-chunk 8, LDS 36KB -> 4 blocks/CU (R4-validated) --------
__global__ __launch_bounds__(256) void k_conv2(
    const float* __restrict__ X1, const float* __restrict__ W2T,
    const float* __restrict__ bb, const float* __restrict__ gg,
    const float* __restrict__ be, const float* __restrict__ mm_,
    const float* __restrict__ vv, float* __restrict__ X2)
{
    __shared__ __align__(16) float xs[36 * 100];    // [tt][ci*12 + m], ci<8
    __shared__ __align__(16) float ws[5 * 8 * 128]; // [dm][ci][co]
    __shared__ float sc[128], sh[128];
    int bid = blockIdx.x;
    int t0 = (bid & 31) << 5, b = bid >> 5;
    int tid = threadIdx.x;
    int tp = tid & 15, cog = tid >> 4;
    if (tid < 128) {
        float s = gg[tid] / sqrtf(vv[tid] + EPSF);
        sc[tid] = s;
        sh[tid] = (bb[tid] - mm_[tid]) * s + be[tid];
    }
    f2 accp[2][4][8];                    // [t-half][co pair][m]
#pragma unroll
    for (int th = 0; th < 2; th++)
#pragma unroll
        for (int p = 0; p < 4; p++)
#pragma unroll
            for (int m = 0; m < 8; m++) accp[th][p][m] = (f2){0.f, 0.f};

    for (int cc = 0; cc < 16; cc++) {
        __syncthreads();
        for (int e = tid; e < 864; e += 256) {
            int ci = e & 7, r = e >> 3;           // r 0..107
            int tt = r / 3, mg = r - tt * 3;
            int gt = t0 + tt - 2;
            float4 v = {0.f, 0.f, 0.f, 0.f};
            if (gt >= 0 && gt < 1024) {
                const float* src = &X1[(((long)(b * 1024 + gt)) * 8) * 128 + cc * 8 + ci];
                float* pv = (float*)&v;
#pragma unroll
                for (int k2 = 0; k2 < 4; k2++) {
                    int gm = mg * 4 + k2 - 2;
                    if (gm >= 0 && gm < 8) pv[k2] = src[gm * 128];
                }
            }
            *(float4*)&xs[tt * 100 + ci * 12 + mg * 4] = v;
        }
        for (int dt = 0; dt < 5; dt++) {
            __syncthreads();
            for (int e = tid; e < 5120; e += 256) {
                int co = e & 127, ci = (e >> 7) & 7, dm = e >> 10;
                ws[dm * 1024 + ci * 128 + co] =
                    W2T[((dt * 5 + dm) * 128 + cc * 8 + ci) * 128 + co];
            }
            __syncthreads();
            for (int ci = 0; ci < 8; ci++) {
                f2 x2[2][6];
#pragma unroll
                for (int th = 0; th < 2; th++) {
                    const float* xp = &xs[(tp + th * 16 + dt) * 100 + ci * 12];
                    f4 a = *(const f4*)&xp[0];
                    f4 bv = *(const f4*)&xp[4];
                    f4 cv = *(const f4*)&xp[8];
                    x2[th][0] = (f2){a.x, a.y};   x2[th][1] = (f2){a.z, a.w};
                    x2[th][2] = (f2){bv.x, bv.y}; x2[th][3] = (f2){bv.z, bv.w};
                    x2[th][4] = (f2){cv.x, cv.y}; x2[th][5] = (f2){cv.z, cv.w};
                }
                const float* wb = &ws[ci * 128];
#pragma unroll
                for (int dm = 0; dm < 5; dm++) {
                    const float* wr = wb + dm * 1024;
                    f4 wa = *(const f4*)&wr[cog * 4];
                    f4 wbv = *(const f4*)&wr[64 + cog * 4];
                    f2 wp[4];
                    wp[0] = (f2){wa.x, wa.y};   wp[1] = (f2){wa.z, wa.w};
                    wp[2] = (f2){wbv.x, wbv.y}; wp[3] = (f2){wbv.z, wbv.w};
#pragma unroll
                    for (int th = 0; th < 2; th++)
#pragma unroll
                        for (int m = 0; m < 8; m++) {
                            const int j = m + dm;
                            f2 xpair = x2[th][j >> 1];
                            if (j & 1) {
                                PK_FMA_HI(accp[th][0][m], wp[0], xpair);
                                PK_FMA_HI(accp[th][1][m], wp[1], xpair);
                                PK_FMA_HI(accp[th][2][m], wp[2], xpair);
                                PK_FMA_HI(accp[th][3][m], wp[3], xpair);
                            } else {
                                PK_FMA_LO(accp[th][0][m], wp[0], xpair);
                                PK_FMA_LO(accp[th][1][m], wp[1], xpair);
                                PK_FMA_LO(accp[th][2][m], wp[2], xpair);
                                PK_FMA_LO(accp[th][3][m], wp[3], xpair);
                            }
                        }
                }
            }
        }
    }
#pragma unroll
    for (int th = 0; th < 2; th++) {
        int t = t0 + th * 16 + tp;
#pragma unroll
        for (int g = 0; g < 2; g++) {
            int cobase = g * 64 + cog * 4;
#pragma unroll
            for (int m2 = 0; m2 < 2; m2++) {
                float4 ov;
                float* po = (float*)&ov;
#pragma unroll
                for (int c = 0; c < 4; c++) {
                    float s = sc[cobase + c], h = sh[cobase + c];
                    float mx = 0.f;
#pragma unroll
                    for (int q = 0; q < 4; q++) {
                        f2 av = accp[th][g * 2 + (c >> 1)][m2 * 4 + q];
                        float a = (c & 1) ? av.y : av.x;
                        float y = fmaf(a, s, h);
                        y = fmaxf(y, 0.f);
                        mx = fmaxf(mx, y);
                    }
                    po[c] = mx;
                }
                *(float4*)&X2[(((long)(b * 1024 + t)) * 2 + m2) * 128 + cobase] = ov;
            }
        }
    }
}

// ------- conv3 v2: t-tile 64, ws staging amortized 4x (R4-validated) -------
__global__ __launch_bounds__(256) void k_conv3(
    const float* __restrict__ X2, const float* __restrict__ W3T,
    const float* __restrict__ bb, const float* __restrict__ gg,
    const float* __restrict__ be, const float* __restrict__ mm_,
    const float* __restrict__ vv, float* __restrict__ F)
{
    __shared__ __align__(16) float xs[68 * 66];     // [t''][ci*2+m], stride 66
    __shared__ __align__(16) float ws[3][32][64];   // [dm-1][ci][co]
    __shared__ float sc[64], sh[64];
    int bid = blockIdx.x;
    int coh = bid & 1, t0 = ((bid >> 1) & 15) << 6, b = bid >> 5;
    int co_base = coh * 64;
    int tid = threadIdx.x;
    int tp = tid & 15, cog = tid >> 4;
    if (tid < 64) {
        int co = co_base + tid;
        float s = gg[co] / sqrtf(vv[co] + EPSF);
        sc[tid] = s;
        sh[tid] = (bb[co] - mm_[co]) * s + be[co];
    }
    float acc[4][4][2];                              // [t-chunk][c][pos]
#pragma unroll
    for (int tc = 0; tc < 4; tc++)
#pragma unroll
        for (int c = 0; c < 4; c++) { acc[tc][c][0] = 0.f; acc[tc][c][1] = 0.f; }

    for (int cc = 0; cc < 4; cc++) {
        __syncthreads();
        for (int e = tid; e < 68 * 64; e += 256) {
            int tt = e >> 6, r = e & 63;
            int ci = r >> 1, m = r & 1;
            int gt = t0 + tt - 2;
            float v = 0.f;
            if (gt >= 0 && gt < 1024)
                v = X2[(((long)(b * 1024 + gt)) * 2 + m) * 128 + cc * 32 + ci];
            xs[tt * 66 + ci * 2 + m] = v;
        }
        for (int dt = 0; dt < 5; dt++) {
            __syncthreads();
            for (int e = tid; e < 3 * 32 * 64; e += 256) {
                int co = e & 63, ci = (e >> 6) & 31, dmi = e >> 11;
                ws[dmi][ci][co] = W3T[((dt * 5 + dmi + 1) * 128 + cc * 32 + ci) * 128 + co_base + co];
            }
            __syncthreads();
            for (int ci = 0; ci < 32; ci++) {
                float w1[4], w2[4], w3[4];
                *(float4*)w1 = *(const float4*)&ws[0][ci][cog * 4];
                *(float4*)w2 = *(const float4*)&ws[1][ci][cog * 4];
                *(float4*)w3 = *(const float4*)&ws[2][ci][cog * 4];
#pragma unroll
                for (int tc = 0; tc < 4; tc++) {
                    float2 x = *(const float2*)&xs[(tc * 16 + tp + dt) * 66 + ci * 2];
#pragma unroll
                    for (int c = 0; c < 4; c++) acc[tc][c][0] = fmaf(w2[c], x.x, acc[tc][c][0]);
#pragma unroll
                    for (int c = 0; c < 4; c++) acc[tc][c][0] = fmaf(w3[c], x.y, acc[tc][c][0]);
#pragma unroll
                    for (int c = 0; c < 4; c++) acc[tc][c][1] = fmaf(w1[c], x.x, acc[tc][c][1]);
#pragma unroll
                    for (int c = 0; c < 4; c++) acc[tc][c][1] = fmaf(w2[c], x.y, acc[tc][c][1]);
                }
            }
        }
    }
#pragma unroll
    for (int tc = 0; tc < 4; tc++) {
        float4 ov;
        float* po = (float*)&ov;
#pragma unroll
        for (int c = 0; c < 4; c++) {
            float s = sc[cog * 4 + c], h = sh[cog * 4 + c];
            float y0 = fmaxf(fmaf(acc[tc][c][0], s, h), 0.f);
            float y1 = fmaxf(fmaf(acc[tc][c][1], s, h), 0.f);
            po[c] = fmaxf(y0, y1);
        }
        *(float4*)&F[((long)(t0 + tc * 16 + tp) * 32 + b) * 128 + co_base + cog * 4] = ov;
    }
}

// ---------------- Gx = F @ Wihx.T + bih : [32768,128]x[128,768] ----------------
__global__ __launch_bounds__(256) void k_gemm(
    const float* __restrict__ F, const float* __restrict__ WxT,
    const float* __restrict__ bih, float* __restrict__ Gx)
{
    __shared__ __align__(16) float Fs[64][33];
    __shared__ __align__(16) float Ws[32][256];
    int bid = blockIdx.x;
    int jt = bid % 3, tb0 = (bid / 3) * 64;
    int tid = threadIdx.x;
    int tx = tid & 31, ty = tid >> 5;
    float acc[8][8];
#pragma unroll
    for (int i = 0; i < 8; i++)
#pragma unroll
        for (int j = 0; j < 8; j++) acc[i][j] = 0.f;
    for (int cc = 0; cc < 4; cc++) {
        __syncthreads();
        for (int e = tid; e < 64 * 32; e += 256) {
            int ci = e & 31, i = e >> 5;
            Fs[i][ci] = F[(long)(tb0 + i) * 128 + cc * 32 + ci];
        }
        for (int e = tid; e < 32 * 256; e += 256) {
            int jj = e & 255, ci = e >> 8;
            Ws[ci][jj] = WxT[(cc * 32 + ci) * 768 + jt * 256 + jj];
        }
        __syncthreads();
        for (int ci = 0; ci < 32; ci++) {
            float a[8], w[8];
#pragma unroll
            for (int i = 0; i < 8; i++) a[i] = Fs[ty * 8 + i][ci];
            *(float4*)&w[0] = *(const float4*)&Ws[ci][tx * 8];
            *(float4*)&w[4] = *(const float4*)&Ws[ci][tx * 8 + 4];
#pragma unroll
            for (int i = 0; i < 8; i++)
#pragma unroll
                for (int j = 0; j < 8; j++) acc[i][j] = fmaf(a[i], w[j], acc[i][j]);
        }
    }
    float bj[8];
#pragma unroll
    for (int j = 0; j < 8; j++) bj[j] = bih[jt * 256 + tx * 8 + j];
#pragma unroll
    for (int i = 0; i < 8; i++) {
        float o[8];
#pragma unroll
        for (int j = 0; j < 8; j++) o[j] = acc[i][j] + bj[j];
        float* dst = &Gx[(long)(tb0 + ty * 8 + i) * 768 + jt * 256 + tx * 8];
        *(float4*)&dst[0] = *(float4*)&o[0];
        *(float4*)&dst[4] = *(float4*)&o[4];
    }
}

// ====== GRU v11: 8-wave MFMA matvec, 192 weight VGPRs/lane (fits 256 cap) ======
// R7 post-mortem: v10 worked (AGPR constraints were the NaN source; "+v" is
// safe) but 384 pinned regs > the 256 arch-VGPR ceiling -> ~150 spilled to
// scratch, gru2 ~2.3ms, and plain-fp16 h left absmax at 0.02148 (margin 8e-5).
// v11: 512 thr / 8 waves / 2 per SIMD. Each wave owns 96 rows = 48 fragments
// = 192 VGPRs; peak live ~245 <= 256. Attribute pattern copied from the R7
// success: launch_bounds(512) with NO second arg + waves_per_eu(2,2) (R2's
// failure used launch_bounds(512,2), which emits a conflicting min).
// Precision restored via hi/lo-in-columns (R6 trick, AGPR-free): B col0 =
// fp16(h), col1 = h - fp16(h); one MFMA pass computes both, dpp(i-1) folds
// them in the col1 lane -> only weight-fp16 rounding remains (absmax ~0.0039).
__global__ __attribute__((amdgpu_waves_per_eu(2, 2))) __launch_bounds__(512) void k_gru2(
    const f16x8* __restrict__ Wp8, const float* __restrict__ Gx,
    const float* __restrict__ Wih, const float* __restrict__ bhh_g,
    const float* __restrict__ Wf, const float* __restrict__ bf_g,
    const float* __restrict__ targets, const unsigned char* __restrict__ fmask,
    const int* __restrict__ flag, float* __restrict__ out)
{
    __shared__ __align__(16) float hq[320];      // swizzled fp32 h (proj)
    __shared__ __align__(16) _Float16 hqh[256];  // fp16(h)      (B col 0)
    __shared__ __align__(16) _Float16 hqh2[256]; // h - fp16(h)  (B col 1)
    __shared__ __align__(16) float gsum[768];
    __shared__ float tfl[16];
    __shared__ float bhL[768];
    __shared__ __align__(16) float wtfL[7680];   // [cp(30)][256]
    __shared__ __align__(16) float WfL[3200];    // [oc(10)][seg*20], padded
    const int b = blockIdx.x, tid = threadIdx.x;
    const int wv = tid >> 6, l = tid & 63;       // wave 0..7
    const int kg = l >> 4;                       // k-group within wave
    const int cl = l & 15;                       // MFMA column of this lane
    const bool isGate = (tid < 256);
    const bool isProj = (tid >= 256 && tid < 416);
    const int oc = (tid - 256) >> 4, seg = tid & 15;
    const bool isWr = isProj && (seg == 15);

    // ---- weights: 48 A-fragments/lane (wave wv owns row-tiles wv*6..+6) ----
    f16x8 wq[48];
    {
        const f16x8* wp = Wp8 + (long)(wv * 48) * 64 + l;
#pragma unroll
        for (int q = 0; q < 48; q++) wq[q] = wp[q * 64];
    }
    // opaque VGPR pin: allocator can neither remat the load nor sink it
#pragma unroll
    for (int q = 0; q < 48; q++) asm volatile("" : "+v"(wq[q]));

    // ---- one-time LDS fills ----
    for (int e = tid; e < 7680; e += 512) {
        int cp = e >> 8, jj = e & 255;
        int gg = cp / 10, c = cp - gg * 10;
        wtfL[e] = Wih[(gg * 256 + jj) * 138 + 128 + c];
    }
    for (int e = tid; e < 3200; e += 512) {
        int oo = e / 320, rem = e - oo * 320;
        int sg = rem / 20, ii = rem - sg * 20;
        WfL[e] = (ii < 16) ? Wf[oo * 256 + sg * 16 + ii] : 0.f;
    }
    for (int e = tid; e < 768; e += 512) { bhL[e] = bhh_g[e]; gsum[e] = 0.f; }
    if (tid < 320) hq[tid] = 0.f;
    if (tid < 256) { hqh[tid] = (_Float16)0.f; hqh2[tid] = (_Float16)0.f; }
    if (tid < 16) tfl[tid] = 0.f;
    float bfc = isProj ? bf_g[oc] : 0.f;
    const int int32mode = flag[0];
    float hold = 0.f;                            // gate thread's h[tid]
    // col-1 lanes feed the residual; all others feed fp16(h)
    const _Float16* bsrc = (cl == 1) ? hqh2 : hqh;
    __syncthreads();

    for (int t = 0; t < 1024; t++) {
        // per-step global loads issued early, consumed after B1
        float gxr = 0.f, gxz = 0.f, gxn = 0.f;
        if (isGate) {
            const float* gx = &Gx[((long)t * 32 + b) * 768];
            gxr = gx[tid]; gxz = gx[tid + 256]; gxn = gx[tid + 512];
        }
        float tgt = 0.f; int fmv = 0;
        if (isWr) {
            tgt = targets[((long)b * 1024 + t) * 10 + oc];
            fmv = int32mode ? ((const int*)fmask)[t * 32 + b] : (int)fmask[t * 32 + b];
        }

        // ---- MFMA matvec: 6 row-tiles x 8 K-tiles, hi|lo in cols 0|1 ----
        f4 acc[6];
#pragma unroll
        for (int rt = 0; rt < 6; rt++) acc[rt] = (f4){0.f, 0.f, 0.f, 0.f};
#pragma unroll
        for (int kt = 0; kt < 8; kt++) {
            f16x8 bv = *(const f16x8*)&bsrc[kt * 32 + kg * 8];
#pragma unroll
            for (int rt = 0; rt < 6; rt++)
                acc[rt] = __builtin_amdgcn_mfma_f32_16x16x32_f16(
                    wq[rt * 8 + kt], bv, acc[rt], 0, 0, 0);
        }
        // col1 lane: acc += col0's value (dpp from lane i-1) = W*hi + W*lo.
        // C/D layout (m89): col=lane&15, row=(lane>>4)*4+reg.
#pragma unroll
        for (int rt = 0; rt < 6; rt++) {
#pragma unroll
            for (int c = 0; c < 4; c++) acc[rt][c] = dpp_add<0x111>(acc[rt][c]);
        }
        if (cl == 1) {
#pragma unroll
            for (int rt = 0; rt < 6; rt++)
                *(f4*)&gsum[(wv * 6 + rt) * 16 + kg * 4] = acc[rt];
        }
        __syncthreads();   // B1: gsum ready; hqh/hqh2 reads of step t complete

        if (isGate) {      // gate phase: 256 threads, one hidden unit each
            float gr = gxr, gz = gxz, gn = gxn;
#pragma unroll
            for (int c = 0; c < 10; c++) {
                float tv = tfl[c];
                gr = fmaf(tv, wtfL[c * 256 + tid], gr);
                gz = fmaf(tv, wtfL[(10 + c) * 256 + tid], gz);
                gn = fmaf(tv, wtfL[(20 + c) * 256 + tid], gn);
            }
            float ar = gsum[tid] + bhL[tid];
            float az = gsum[tid + 256] + bhL[tid + 256];
            float an = gsum[tid + 512] + bhL[tid + 512];
            float r = 1.0f / (1.0f + expf(-(gr + ar)));
            float z = 1.0f / (1.0f + expf(-(gz + az)));
            float n = tanhf(fmaf(r, an, gn));
            float hnew = (1.0f - z) * n + z * hold;
            hold = hnew;
            _Float16 hh = (_Float16)hnew;
            hq[HQ(tid)] = hnew;
            hqh[tid] = hh;
            hqh2[tid] = (_Float16)(hnew - (float)hh);
        }
        __syncthreads();   // B2: h ready

        if (isProj) {
            float s = 0.f;
#pragma unroll
            for (int qq = 0; qq < 4; qq++) {
                f4 h4 = *(const f4*)&hq[seg * 20 + qq * 4];
                f4 wvv = *(const f4*)&WfL[oc * 320 + seg * 20 + qq * 4];
                s = fmaf(wvv.x, h4.x, s);
                s = fmaf(wvv.y, h4.y, s);
                s = fmaf(wvv.z, h4.z, s);
                s = fmaf(wvv.w, h4.w, s);
            }
            s = dpp_add<0x111>(s);
            s = dpp_add<0x112>(s);
            s = dpp_add<0x114>(s);
            s = dpp_add<0x118>(s);
            if (isWr) {
                float o = s + bfc;
                out[((long)b * 1024 + t) * 10 + oc] = o;
                float pred = (o > 0.f) ? 1.f : 0.f;
                tfl[oc] = fmv ? tgt : pred;
            }
        }
        // ordering: gates(t) read gsum between B1(t) and B2(t); matvec(t+1)
        // writes gsum only after B2(t) (all waves past gate reads). matvec
        // reads hqh/hqh2 after B2 (gates wrote before B2). proj reads hq/tfl
        // between B2(t) and B1(t+1); gates touch them after B1(t+1). No races.
    }
}

extern "C" void kernel_launch(void* const* d_in, const int* in_sizes, int n_in,
                              void* d_out, int out_size, void* d_ws, size_t ws_size,
                              hipStream_t stream) {
    (void)in_sizes; (void)n_in; (void)out_size; (void)ws_size;
    const float* features = (const float*)d_in[0];
    const float* targets  = (const float*)d_in[1];
    const unsigned char* fmask = (const unsigned char*)d_in[2];
    const float* W1  = (const float*)d_in[3];
    const float* b1  = (const float*)d_in[4];
    const float* g1  = (const float*)d_in[5];
    const float* be1 = (const float*)d_in[6];
    const float* m1  = (const float*)d_in[7];
    const float* v1  = (const float*)d_in[8];
    const float* W2  = (const float*)d_in[9];
    const float* b2  = (const float*)d_in[10];
    const float* g2  = (const float*)d_in[11];
    const float* be2 = (const float*)d_in[12];
    const float* m2  = (const float*)d_in[13];
    const float* v2  = (const float*)d_in[14];
    const float* W3  = (const float*)d_in[15];
    const float* b3  = (const float*)d_in[16];
    const float* g3  = (const float*)d_in[17];
    const float* be3 = (const float*)d_in[18];
    const float* m3  = (const float*)d_in[19];
    const float* v3  = (const float*)d_in[20];
    const float* Wih = (const float*)d_in[21];
    const float* Whh = (const float*)d_in[22];
    const float* bih = (const float*)d_in[23];
    const float* bhh = (const float*)d_in[24];
    const float* Wf  = (const float*)d_in[25];
    const float* bf  = (const float*)d_in[26];

    char* w = (char*)d_ws;
    unsigned int* WhhP = (unsigned int*)(w + 0);        // 393216 B (in 786432 slot)
    float* WxT = (float*)(w + 786432);                  // 393216 B
    float* W2T = (float*)(w + 1179648);                 // 1638400 B
    float* W3T = (float*)(w + 2818048);                 // 1638400 B
    int*   flag = (int*)(w + 4456448);                  // 512 B slot
    float* X1  = (float*)(w + 4456960);                 // 128 MB; reused as Gx after conv2
    float* Gx  = X1;
    float* X2  = (float*)(w + 4456960 + 134217728);     // 32 MB
    float* F   = (float*)(w + 4456960 + 134217728 + 33554432); // 16 MB
    float* out = (float*)d_out;

    k_prep<<<1600, 256, 0, stream>>>(Wih, Whh, W2, W3, fmask, WhhP, WxT, W2T, W3T, flag);
    k_conv1<<<8192, 256, 0, stream>>>(features, W1, b1, g1, be1, m1, v1, X1);
    k_conv2<<<1024, 256, 0, stream>>>(X1, W2T, b2, g2, be2, m2, v2, X2);
    k_conv3<<<1024, 256, 0, stream>>>(X2, W3T, b3, g3, be3, m3, v3, F);
    k_gemm<<<1536, 256, 0, stream>>>(F, WxT, bih, Gx);
    k_gru2<<<32, 512, 0, stream>>>((const f16x8*)WhhP, Gx, Wih, bhh, Wf, bf,
                                   targets, fmask, flag, out);
}